// Round 16
// baseline (316.772 us; speedup 1.0000x reference)
//
#include <hip/hip_runtime.h>
#include <math.h>

#define F1 100
#define F2 200
#define KM 16          // Chebyshev moments
#define BW_LOG 9
#define BW 512
#define MP 17          // padded moment row (bank-conflict-free LDS atomics)

__device__ __forceinline__ float siluf(float v) {
    return v / (1.0f + expf(-v));   // precise
}
__device__ __forceinline__ float silu_fast(float v) {
    return __fdividef(v, 1.0f + __expf(-v));
}

// batch is sorted: counts via binary-searched boundaries.
__global__ void k_batch_bounds(const int* __restrict__ batch, int N, int G,
                               int* __restrict__ starts, int* __restrict__ counts) {
    int t = threadIdx.x;
    if (t <= G) {
        int lo = 0, hi = N;
        while (lo < hi) {
            int mid = (lo + hi) >> 1;
            if (batch[mid] < t) lo = mid + 1; else hi = mid;
        }
        starts[t] = lo;
    }
    __syncthreads();
    if (t < G) counts[t] = starts[t + 1] - starts[t];
}

// ---- bucketed edge staging ----
__global__ __launch_bounds__(256) void k_bucket_count(const int* __restrict__ dst, int E,
                                                      int nbk, int* __restrict__ gcnt) {
    extern __shared__ int cnt[];
    for (int i = threadIdx.x; i < nbk; i += 256) cnt[i] = 0;
    __syncthreads();
    for (int e = blockIdx.x * 256 + threadIdx.x; e < E; e += gridDim.x * 256)
        atomicAdd(&cnt[dst[e] >> BW_LOG], 1);
    __syncthreads();
    for (int i = threadIdx.x; i < nbk; i += 256)
        if (cnt[i]) atomicAdd(&gcnt[i], cnt[i]);
}

__global__ __launch_bounds__(256) void k_bucket_scan(const int* __restrict__ gcnt, int nbk, int E,
                                                     int* __restrict__ base, int* __restrict__ cursor) {
    __shared__ int sh[256];
    int t = threadIdx.x;
    int v = (t < nbk) ? gcnt[t] : 0;
    sh[t] = v;
    __syncthreads();
    for (int ofs = 1; ofs < 256; ofs <<= 1) {
        int u = (t >= ofs) ? sh[t - ofs] : 0;
        __syncthreads();
        sh[t] += u;
        __syncthreads();
    }
    if (t < nbk) { int ex = sh[t] - v; base[t] = ex; cursor[t] = ex; }
    if (t == 0) base[nbk] = E;
}

#define CROUND 2048
__global__ __launch_bounds__(256) void k_bucket_scatter(
    const int* __restrict__ src, const int* __restrict__ dst, int E, int nbk,
    int* __restrict__ gcursor, unsigned long long* __restrict__ pairs) {
    __shared__ int cnt[256];
    __shared__ int scanb[256];
    __shared__ int startx[256];
    __shared__ int cur[256];
    __shared__ int gbase[256];
    __shared__ unsigned long long stage[CROUND];
    int tid = threadIdx.x;
    for (long long r0 = (long long)blockIdx.x * CROUND; r0 < E; r0 += (long long)gridDim.x * CROUND) {
        cnt[tid] = 0;
        __syncthreads();
        int ss[8], dd[8], bb[8];
        bool va[8];
        #pragma unroll
        for (int j = 0; j < 8; ++j) {
            long long e = r0 + j * 256 + tid;
            va[j] = (e < E);
            if (va[j]) {
                ss[j] = src[e]; dd[j] = dst[e]; bb[j] = dd[j] >> BW_LOG;
                atomicAdd(&cnt[bb[j]], 1);
            }
        }
        __syncthreads();
        scanb[tid] = cnt[tid];
        __syncthreads();
        for (int ofs = 1; ofs < 256; ofs <<= 1) {
            int u = (tid >= ofs) ? scanb[tid - ofs] : 0;
            __syncthreads();
            scanb[tid] += u;
            __syncthreads();
        }
        int ex = scanb[tid] - cnt[tid];
        startx[tid] = ex;
        cur[tid] = ex;
        if (tid < nbk && cnt[tid] > 0) gbase[tid] = atomicAdd(&gcursor[tid], cnt[tid]);
        __syncthreads();
        int total = scanb[255];
        #pragma unroll
        for (int j = 0; j < 8; ++j) {
            if (va[j]) {
                int slot = atomicAdd(&cur[bb[j]], 1);
                stage[slot] = ((unsigned long long)(unsigned)dd[j] << 32) | (unsigned)ss[j];
            }
        }
        __syncthreads();
        for (int i = tid; i < total; i += 256) {
            unsigned long long p = stage[i];
            int b = (int)(p >> 32) >> BW_LOG;
            pairs[gbase[b] + (i - startx[b])] = p;
        }
        __syncthreads();
    }
}

// A: per-bucket degree histogram -> dinv, y = x*dinv. (No CSR off/scan needed.)
__global__ __launch_bounds__(512) void k_bucket_deg2(
    const unsigned long long* __restrict__ pairs, const int* __restrict__ bbase,
    const float* __restrict__ x, int N,
    float* __restrict__ dinv, float* __restrict__ y) {
    __shared__ int dl[BW];
    int b = blockIdx.x;
    int t = threadIdx.x;
    dl[t] = 0;
    __syncthreads();
    int beg = bbase[b], end = bbase[b + 1];
    for (int i = beg + t; i < end; i += 512)
        atomicAdd(&dl[(int)(pairs[i] >> 32) & (BW - 1)], 1);
    __syncthreads();
    int node = (b << BW_LOG) + t;
    if (node < N) {
        float d = 1.0f / sqrtf((float)dl[t] + 1.0f);
        dinv[node] = d;
        y[node] = x[node] * d;
    }
}

// B: per-bucket layer-1 scalar agg -> aggxd {aggx, dinv}; block-max |aggx| -> amax.
__global__ __launch_bounds__(512) void k_bucket_aggx(
    const unsigned long long* __restrict__ pairs, const int* __restrict__ bbase,
    const float* __restrict__ y, const float* __restrict__ dinv, int N,
    float2* __restrict__ aggxd, unsigned* __restrict__ amax) {
    __shared__ float agg[BW];
    int b = blockIdx.x;
    int t = threadIdx.x;
    agg[t] = 0.0f;
    __syncthreads();
    int beg = bbase[b], end = bbase[b + 1];
    for (int i = beg + t; i < end; i += 512) {
        unsigned long long p = pairs[i];
        int s = (int)(p & 0xffffffffu);
        int l = (int)(p >> 32) & (BW - 1);
        atomicAdd(&agg[l], y[s]);
    }
    __syncthreads();
    float av = 0.0f;
    int node = (b << BW_LOG) + t;
    if (node < N) {
        float dn = dinv[node];
        float a = dn * (agg[t] + y[node]);   // y[node] = x*dinv, same value as before
        aggxd[node] = make_float2(a, dn);
        av = fabsf(a);
    }
    __syncthreads();
    agg[t] = av;
    __syncthreads();
    for (int ofs = 256; ofs > 0; ofs >>= 1) {
        if (t < ofs) agg[t] = fmaxf(agg[t], agg[t + ofs]);
        __syncthreads();
    }
    if (t == 0) atomicMax(amax, __float_as_uint(agg[0]));
}

// Fit stage 1: Chebyshev coefficients cl[k][j] of g(a,j)=silu(a*W1[j]+b1[j]) on [-A,A].
__global__ __launch_bounds__(64) void k_fit_coef(
    const float* __restrict__ W1, const float* __restrict__ b1,
    const unsigned* __restrict__ amax_bits,
    double* __restrict__ cl /* [KM][F1] */, float* __restrict__ scal /* {A, invA} */) {
    int j = blockIdx.x;
    int i = threadIdx.x;
    float A = __uint_as_float(*amax_bits);
    if (!(A > 0.0f)) A = 1.0f;
    A *= 1.000001f;
    if (j == 0 && i == 0) { scal[0] = A; scal[1] = 1.0f / A; }
    const double PI = 3.14159265358979323846;
    double th = (i + 0.5) * (PI / 64.0);
    double xx = cos(th);
    double w = (double)W1[j] * (double)A;
    double u = w * xx + (double)b1[j];
    double f = u / (1.0 + exp(-u));
    double acc[KM];
    {
        double c0 = 1.0, c1 = xx;
        acc[0] = f;
        acc[1] = f * xx;
        #pragma unroll
        for (int k = 2; k < KM; ++k) {
            double c2 = 2.0 * xx * c1 - c0;
            acc[k] = f * c2;
            c0 = c1; c1 = c2;
        }
    }
    #pragma unroll
    for (int k = 0; k < KM; ++k) {
        double v = acc[k];
        for (int ofs = 32; ofs > 0; ofs >>= 1)
            v += __shfl_down(v, ofs);
        if (i == 0) cl[k * F1 + j] = v * ((k == 0 ? 1.0 : 2.0) / 64.0);
    }
}

// Fit stage 2: fold through W2: D[k][m] = sum_j cl[k][j] * W2[j][m].
__global__ __launch_bounds__(256) void k_fit_fold(
    const double* __restrict__ cl, const float* __restrict__ W2,
    float* __restrict__ Dmat /* [KM][F2] */) {
    __shared__ double scl[KM * F1];
    int tid = threadIdx.x;
    for (int idx = tid; idx < KM * F1; idx += 256) scl[idx] = cl[idx];
    __syncthreads();
    int idx = blockIdx.x * 256 + tid;
    if (idx >= KM * F2) return;
    int k = idx / F2, m = idx % F2;
    double s = 0.0;
    #pragma unroll 4
    for (int j = 0; j < F1; ++j)
        s += scl[k * F1 + j] * (double)W2[j * F2 + m];
    Dmat[idx] = (float)s;
}

// C: per-bucket edge-parallel moments via padded LDS atomics.
// U_k[d] = sum_{s in N(d)} dinv_s * T_k(a_s/A); M_k = d0*(U_k + d0*T_k(a_n/A)).
// ml pad 17 -> bank = (l*17+k)%32 spreads across all banks (random dests ~2 lanes/bank).
__global__ __launch_bounds__(512) void k_bucket_moments(
    const unsigned long long* __restrict__ pairs, const int* __restrict__ bbase,
    const float2* __restrict__ aggxd, const float* __restrict__ scal, int N,
    float* __restrict__ Mrow /* [N][KM] */) {
    __shared__ float ml[BW * MP];   // 34816 B
    int b = blockIdx.x;
    int t = threadIdx.x;
    for (int i = t; i < BW * MP; i += 512) ml[i] = 0.0f;
    __syncthreads();
    float invA = scal[1];
    int beg = bbase[b], end = bbase[b + 1];
    for (int i = beg + t; i < end; i += 512) {
        unsigned long long p = pairs[i];
        int s = (int)(p & 0xffffffffu);
        int l = (int)(p >> 32) & (BW - 1);
        float2 q = aggxd[s];
        float w = q.y;              // dinv_s
        float xa = q.x * invA;
        float tx = xa + xa;
        float* mb = &ml[l * MP];
        float c0 = 1.0f, c1 = xa;
        atomicAdd(&mb[0], w);
        atomicAdd(&mb[1], w * xa);
        #pragma unroll
        for (int k = 2; k < KM; ++k) {
            float c2 = fmaf(tx, c1, -c0);
            atomicAdd(&mb[k], w * c2);
            c0 = c1; c1 = c2;
        }
    }
    __syncthreads();
    int node = (b << BW_LOG) + t;
    if (node < N) {
        float2 sd = aggxd[node];
        float d0 = sd.y;
        float xa = sd.x * invA;
        float tx = xa + xa;
        const float* mb = &ml[t * MP];
        float m[KM];
        float c0 = 1.0f, c1 = xa;
        m[0] = d0 * (mb[0] + d0);
        m[1] = d0 * (mb[1] + d0 * xa);
        #pragma unroll
        for (int k = 2; k < KM; ++k) {
            float c2 = fmaf(tx, c1, -c0);
            m[k] = d0 * (mb[k] + d0 * c2);
            c0 = c1; c1 = c2;
        }
        float4* out4 = (float4*)(Mrow + (size_t)node * KM);
        out4[0] = make_float4(m[0], m[1], m[2], m[3]);
        out4[1] = make_float4(m[4], m[5], m[6], m[7]);
        out4[2] = make_float4(m[8], m[9], m[10], m[11]);
        out4[3] = make_float4(m[12], m[13], m[14], m[15]);
    }
}

// Fused h2 = silu(M @ D + b2) + graph mean-pool numerator (2-node ILP unroll).
#define P6_NODES 32
__global__ __launch_bounds__(256) void k_h2_pool6(
    const float* __restrict__ Mrow, const float* __restrict__ Dmat,
    const float* __restrict__ b2, const int* __restrict__ batch,
    int N, double* __restrict__ pooled) {
    __shared__ float sM[P6_NODES][KM];   // 2 KB
    __shared__ int sbatch[P6_NODES];
    int tid = threadIdx.x;
    int base = blockIdx.x * P6_NODES;
    if (tid < P6_NODES * 4) {
        int node = tid >> 2, q = tid & 3;
        float4 v = make_float4(0.f, 0.f, 0.f, 0.f);
        if (base + node < N)
            v = ((const float4*)(Mrow + (size_t)(base + node) * KM))[q];
        ((float4*)&sM[node][0])[q] = v;
    }
    if (tid < P6_NODES) {
        int n = base + tid;
        sbatch[tid] = (n < N) ? batch[n] : -1;
    }
    int m = tid;
    bool act = (m < F2);
    float4 d4[KM / 4];
    float bb = 0.0f;
    if (act) {
        #pragma unroll
        for (int k = 0; k < KM / 4; ++k) {
            d4[k].x = Dmat[(4 * k + 0) * F2 + m];
            d4[k].y = Dmat[(4 * k + 1) * F2 + m];
            d4[k].z = Dmat[(4 * k + 2) * F2 + m];
            d4[k].w = Dmat[(4 * k + 3) * F2 + m];
        }
        bb = b2[m];
    }
    __syncthreads();
    double pl = 0.0;
    int gcur = -1;
    int nlim = min(P6_NODES, N - base);
    int i = 0;
    for (; i + 1 < nlim; i += 2) {
        float preA, preB;
        {
            const float4* mA = (const float4*)&sM[i][0];
            const float4* mB = (const float4*)&sM[i + 1][0];
            float4 a0 = mA[0], a1 = mA[1], a2 = mA[2], a3 = mA[3];
            float4 c0 = mB[0], c1 = mB[1], c2 = mB[2], c3 = mB[3];
            float p0 = bb, p1 = 0.f, p2 = 0.f, p3 = 0.f;
            float q0 = bb, q1 = 0.f, q2 = 0.f, q3 = 0.f;
            p0 = fmaf(a0.x, d4[0].x, p0); q0 = fmaf(c0.x, d4[0].x, q0);
            p1 = fmaf(a0.y, d4[0].y, p1); q1 = fmaf(c0.y, d4[0].y, q1);
            p2 = fmaf(a0.z, d4[0].z, p2); q2 = fmaf(c0.z, d4[0].z, q2);
            p3 = fmaf(a0.w, d4[0].w, p3); q3 = fmaf(c0.w, d4[0].w, q3);
            p0 = fmaf(a1.x, d4[1].x, p0); q0 = fmaf(c1.x, d4[1].x, q0);
            p1 = fmaf(a1.y, d4[1].y, p1); q1 = fmaf(c1.y, d4[1].y, q1);
            p2 = fmaf(a1.z, d4[1].z, p2); q2 = fmaf(c1.z, d4[1].z, q2);
            p3 = fmaf(a1.w, d4[1].w, p3); q3 = fmaf(c1.w, d4[1].w, q3);
            p0 = fmaf(a2.x, d4[2].x, p0); q0 = fmaf(c2.x, d4[2].x, q0);
            p1 = fmaf(a2.y, d4[2].y, p1); q1 = fmaf(c2.y, d4[2].y, q1);
            p2 = fmaf(a2.z, d4[2].z, p2); q2 = fmaf(c2.z, d4[2].z, q2);
            p3 = fmaf(a2.w, d4[2].w, p3); q3 = fmaf(c2.w, d4[2].w, q3);
            p0 = fmaf(a3.x, d4[3].x, p0); q0 = fmaf(c3.x, d4[3].x, q0);
            p1 = fmaf(a3.y, d4[3].y, p1); q1 = fmaf(c3.y, d4[3].y, q1);
            p2 = fmaf(a3.z, d4[3].z, p2); q2 = fmaf(c3.z, d4[3].z, q2);
            p3 = fmaf(a3.w, d4[3].w, p3); q3 = fmaf(c3.w, d4[3].w, q3);
            preA = (p0 + p1) + (p2 + p3);
            preB = (q0 + q1) + (q2 + q3);
        }
        float hA = silu_fast(preA);
        float hB = silu_fast(preB);
        int g = sbatch[i];
        if (g != gcur) {
            if (gcur >= 0 && act) atomicAdd(&pooled[(size_t)gcur * F2 + m], pl);
            pl = 0.0;
            gcur = g;
        }
        if (act) pl += (double)hA;
        g = sbatch[i + 1];
        if (g != gcur) {
            if (gcur >= 0 && act) atomicAdd(&pooled[(size_t)gcur * F2 + m], pl);
            pl = 0.0;
            gcur = g;
        }
        if (act) pl += (double)hB;
    }
    if (i < nlim) {
        const float4* m4 = (const float4*)&sM[i][0];
        float4 a0 = m4[0], a1 = m4[1], a2 = m4[2], a3 = m4[3];
        float p0 = bb, p1 = 0.f, p2 = 0.f, p3 = 0.f;
        p0 = fmaf(a0.x, d4[0].x, p0); p1 = fmaf(a0.y, d4[0].y, p1);
        p2 = fmaf(a0.z, d4[0].z, p2); p3 = fmaf(a0.w, d4[0].w, p3);
        p0 = fmaf(a1.x, d4[1].x, p0); p1 = fmaf(a1.y, d4[1].y, p1);
        p2 = fmaf(a1.z, d4[1].z, p2); p3 = fmaf(a1.w, d4[1].w, p3);
        p0 = fmaf(a2.x, d4[2].x, p0); p1 = fmaf(a2.y, d4[2].y, p1);
        p2 = fmaf(a2.z, d4[2].z, p2); p3 = fmaf(a2.w, d4[2].w, p3);
        p0 = fmaf(a3.x, d4[3].x, p0); p1 = fmaf(a3.y, d4[3].y, p1);
        p2 = fmaf(a3.z, d4[3].z, p2); p3 = fmaf(a3.w, d4[3].w, p3);
        float pre = (p0 + p1) + (p2 + p3);
        int g = sbatch[i];
        if (g != gcur) {
            if (gcur >= 0 && act) atomicAdd(&pooled[(size_t)gcur * F2 + m], pl);
            pl = 0.0;
            gcur = g;
        }
        if (act) pl += (double)silu_fast(pre);
    }
    if (gcur >= 0 && act) atomicAdd(&pooled[(size_t)gcur * F2 + m], pl);
}

// ---- fallback path kernels (ws too small for pairs) ----
#define SCHUNK 2048
__global__ __launch_bounds__(256) void k_scan_partial(const int* __restrict__ deg, int N,
                                                      int* __restrict__ partials) {
    __shared__ int red[256];
    int base = blockIdx.x * SCHUNK;
    int s = 0;
    for (int i = threadIdx.x; i < SCHUNK; i += 256) {
        int idx = base + i;
        if (idx < N) s += deg[idx];
    }
    red[threadIdx.x] = s;
    __syncthreads();
    for (int ofs = 128; ofs > 0; ofs >>= 1) {
        if (threadIdx.x < ofs) red[threadIdx.x] += red[threadIdx.x + ofs];
        __syncthreads();
    }
    if (threadIdx.x == 0) partials[blockIdx.x] = red[0];
}
__global__ __launch_bounds__(1024) void k_scan_blocks(int* __restrict__ partials, int nb) {
    __shared__ int sh[1024];
    int t = threadIdx.x;
    int v = (t < nb) ? partials[t] : 0;
    sh[t] = v;
    __syncthreads();
    for (int ofs = 1; ofs < 1024; ofs <<= 1) {
        int u = (t >= ofs) ? sh[t - ofs] : 0;
        __syncthreads();
        sh[t] += u;
        __syncthreads();
    }
    if (t < nb) partials[t] = sh[t] - v;
}
__global__ __launch_bounds__(256) void k_scan_final(const int* __restrict__ deg, int N,
                                                    const int* __restrict__ partials,
                                                    int* __restrict__ off) {
    __shared__ int sh[256];
    int base = blockIdx.x * SCHUNK;
    int i0 = base + threadIdx.x * 8;
    int v[8];
    int s = 0;
    #pragma unroll
    for (int j = 0; j < 8; ++j) {
        int idx = i0 + j;
        v[j] = (idx < N) ? deg[idx] : 0;
        s += v[j];
    }
    int mine = s;
    sh[threadIdx.x] = s;
    __syncthreads();
    for (int ofs = 1; ofs < 256; ofs <<= 1) {
        int u = (threadIdx.x >= ofs) ? sh[threadIdx.x - ofs] : 0;
        __syncthreads();
        sh[threadIdx.x] += u;
        __syncthreads();
    }
    int run = partials[blockIdx.x] + sh[threadIdx.x] - mine;
    #pragma unroll
    for (int j = 0; j < 8; ++j) {
        int idx = i0 + j;
        if (idx < N) { off[idx] = run; run += v[j]; }
    }
    if (N >= i0 && N <= i0 + 8) off[N] = run;
}
__global__ void k_count_deg(const int* __restrict__ dst, int E, int* __restrict__ deg) {
    int i = blockIdx.x * blockDim.x + threadIdx.x;
    if (i < E) atomicAdd(&deg[dst[i]], 1);
}
__global__ void k_dinv_self(const int* __restrict__ deg, const float* __restrict__ x, int N,
                            float* __restrict__ dinv, float* __restrict__ aggx) {
    int i = blockIdx.x * blockDim.x + threadIdx.x;
    if (i < N) {
        float d = 1.0f / sqrtf((float)deg[i] + 1.0f);
        dinv[i] = d;
        aggx[i] = x[i] * d * d;
    }
}
__global__ void k_fill_agg(const int* __restrict__ src, const int* __restrict__ dst, int E,
                           const int* __restrict__ off, int* __restrict__ cursor,
                           int* __restrict__ nbr,
                           const float* __restrict__ x, const float* __restrict__ dinv,
                           float* __restrict__ aggx) {
    int e = blockIdx.x * blockDim.x + threadIdx.x;
    if (e < E) {
        int s = src[e], d = dst[e];
        int p = atomicAdd(&cursor[d], 1);
        nbr[off[d] + p] = s;
        atomicAdd(&aggx[d], x[s] * dinv[s] * dinv[d]);
    }
}
__global__ __launch_bounds__(256) void k_aggh(
    const int* __restrict__ off, const int* __restrict__ nbr,
    const float* __restrict__ aggx, const float* __restrict__ dinv,
    const float* __restrict__ W1, const float* __restrict__ b1,
    int N, float* __restrict__ aggh) {
    int wave = threadIdx.x >> 6;
    int lane = threadIdx.x & 63;
    int n = blockIdx.x * 4 + wave;
    if (n >= N) return;
    int ja = lane, jb = lane + 64;
    float w1a = (ja < F1) ? W1[ja] : 0.0f;
    float b1a = (ja < F1) ? b1[ja] : 0.0f;
    float w1b = (jb < F1) ? W1[jb] : 0.0f;
    float b1b = (jb < F1) ? b1[jb] : 0.0f;
    float d0 = dinv[n];
    float a0 = aggx[n];
    float accA = silu_fast(fmaf(a0, w1a, b1a)) * (d0 * d0);
    float accB = silu_fast(fmaf(a0, w1b, b1b)) * (d0 * d0);
    int beg = off[n], end = off[n + 1];
    for (int t = beg; t < end; t += 64) {
        int cnt = min(64, end - t);
        float sa = 0.0f, sw = 0.0f;
        if (lane < cnt) {
            int s = nbr[t + lane];
            sa = aggx[s];
            sw = dinv[s] * d0;
        }
        for (int i = 0; i < cnt; ++i) {
            float ai = __shfl(sa, i);
            float wi = __shfl(sw, i);
            accA = fmaf(wi, silu_fast(fmaf(ai, w1a, b1a)), accA);
            accB = fmaf(wi, silu_fast(fmaf(ai, w1b, b1b)), accB);
        }
    }
    if (ja < F1) aggh[(size_t)n * F1 + ja] = accA;
    if (jb < F1) aggh[(size_t)n * F1 + jb] = accB;
}
#define HP_NODES 20
#define HP_KT 25
__global__ __launch_bounds__(256) void k_h2_pool3(
    const float* __restrict__ aggh, const float* __restrict__ W2, const float* __restrict__ b2,
    const int* __restrict__ batch, int N, double* __restrict__ pooled) {
    __shared__ float smem[HP_KT * F2 + HP_NODES * (F1 + 1)];
    float* sW = smem;
    float* sA = smem + HP_KT * F2;
    float* sOut = smem;
    __shared__ int sbatch[HP_NODES];
    int tid = threadIdx.x;
    int base = blockIdx.x * HP_NODES;
    for (int idx = tid; idx < HP_NODES * (F1 / 4); idx += 256) {
        int i = idx / (F1 / 4), q = idx % (F1 / 4);
        int n = base + i;
        float4 v = make_float4(0.f, 0.f, 0.f, 0.f);
        if (n < N) v = *(const float4*)(aggh + (size_t)n * F1 + q * 4);
        float* dp = &sA[i * (F1 + 1) + q * 4];
        dp[0] = v.x; dp[1] = v.y; dp[2] = v.z; dp[3] = v.w;
    }
    if (tid < HP_NODES) {
        int n = base + tid;
        sbatch[tid] = (n < N) ? batch[n] : -1;
    }
    const int fgrp = tid % 50;
    const int ngrp = tid / 50;
    const int m0 = fgrp * 4;
    const int i0 = ngrp * 4;
    const bool act = (tid < 250);
    float acc[4][4];
    #pragma unroll
    for (int i = 0; i < 4; ++i)
        #pragma unroll
        for (int j = 0; j < 4; ++j) acc[i][j] = 0.0f;
    for (int kt = 0; kt < F1; kt += HP_KT) {
        __syncthreads();
        for (int idx = tid; idx < (HP_KT * F2) / 4; idx += 256)
            ((float4*)sW)[idx] = ((const float4*)(W2 + (size_t)kt * F2))[idx];
        __syncthreads();
        if (act) {
            #pragma unroll
            for (int kk = 0; kk < HP_KT; ++kk) {
                float4 w = *(const float4*)&sW[kk * F2 + m0];
                int k = kt + kk;
                float a0 = sA[(i0 + 0) * (F1 + 1) + k];
                float a1 = sA[(i0 + 1) * (F1 + 1) + k];
                float a2 = sA[(i0 + 2) * (F1 + 1) + k];
                float a3 = sA[(i0 + 3) * (F1 + 1) + k];
                acc[0][0] = fmaf(a0, w.x, acc[0][0]); acc[0][1] = fmaf(a0, w.y, acc[0][1]);
                acc[0][2] = fmaf(a0, w.z, acc[0][2]); acc[0][3] = fmaf(a0, w.w, acc[0][3]);
                acc[1][0] = fmaf(a1, w.x, acc[1][0]); acc[1][1] = fmaf(a1, w.y, acc[1][1]);
                acc[1][2] = fmaf(a1, w.z, acc[1][2]); acc[1][3] = fmaf(a1, w.w, acc[1][3]);
                acc[2][0] = fmaf(a2, w.x, acc[2][0]); acc[2][1] = fmaf(a2, w.y, acc[2][1]);
                acc[2][2] = fmaf(a2, w.z, acc[2][2]); acc[2][3] = fmaf(a2, w.w, acc[2][3]);
                acc[3][0] = fmaf(a3, w.x, acc[3][0]); acc[3][1] = fmaf(a3, w.y, acc[3][1]);
                acc[3][2] = fmaf(a3, w.z, acc[3][2]); acc[3][3] = fmaf(a3, w.w, acc[3][3]);
            }
        }
    }
    __syncthreads();
    if (act) {
        float4 bb = *(const float4*)(b2 + m0);
        #pragma unroll
        for (int i = 0; i < 4; ++i) {
            float4 r;
            r.x = siluf(acc[i][0] + bb.x);
            r.y = siluf(acc[i][1] + bb.y);
            r.z = siluf(acc[i][2] + bb.z);
            r.w = siluf(acc[i][3] + bb.w);
            *(float4*)&sOut[(i0 + i) * F2 + m0] = r;
        }
    }
    __syncthreads();
    if (tid < F2) {
        double pl = 0.0;
        int gcur = -1;
        for (int i = 0; i < HP_NODES; ++i) {
            int n = base + i;
            if (n >= N) break;
            int g = sbatch[i];
            if (g != gcur) {
                if (gcur >= 0) atomicAdd(&pooled[(size_t)gcur * F2 + tid], pl);
                pl = 0.0;
                gcur = g;
            }
            pl += (double)sOut[i * F2 + tid];
        }
        if (gcur >= 0) atomicAdd(&pooled[(size_t)gcur * F2 + tid], pl);
    }
}

// Head MLP: one block per graph, double precision.
__global__ __launch_bounds__(256) void k_head(
    const double* __restrict__ pooled, const int* __restrict__ counts,
    const float* __restrict__ Wl1, const float* __restrict__ bl1,
    const float* __restrict__ Wl2, const float* __restrict__ bl2,
    float* __restrict__ out) {
    int g = blockIdx.x;
    int tid = threadIdx.x;
    __shared__ double sp[F2];
    __shared__ double red[256];
    double icnt = 1.0 / (double)max(counts[g], 1);
    for (int m = tid; m < F2; m += 256) sp[m] = pooled[(size_t)g * F2 + m] * icnt;
    __syncthreads();
    double part = 0.0;
    if (tid < 100) {
        double acc = (double)bl1[tid];
        #pragma unroll 4
        for (int m = 0; m < F2; ++m) acc += sp[m] * (double)Wl1[m * 100 + tid];
        double t1 = acc / (1.0 + exp(-acc));
        part = t1 * (double)Wl2[tid];
    }
    red[tid] = part;
    __syncthreads();
    for (int s = 128; s > 0; s >>= 1) {
        if (tid < s) red[tid] += red[tid + s];
        __syncthreads();
    }
    if (tid == 0) out[g] = (float)(red[0] + (double)bl2[0]);
}

extern "C" void kernel_launch(void* const* d_in, const int* in_sizes, int n_in,
                              void* d_out, int out_size, void* d_ws, size_t ws_size,
                              hipStream_t stream)
{
    const float* x   = (const float*)d_in[0];
    const int*   src = (const int*)d_in[1];
    const int*   dst = (const int*)d_in[2];
    const int*   batch = (const int*)d_in[3];
    const float* W1  = (const float*)d_in[4];
    const float* b1  = (const float*)d_in[5];
    const float* W2  = (const float*)d_in[6];
    const float* b2  = (const float*)d_in[7];
    const float* Wl1 = (const float*)d_in[8];
    const float* bl1 = (const float*)d_in[9];
    const float* Wl2 = (const float*)d_in[10];
    const float* bl2 = (const float*)d_in[11];
    int N = in_sizes[0];
    int E = in_sizes[1];
    int G = out_size;
    float* out = (float*)d_out;

    char* ws = (char*)d_ws;
    size_t o = 0;
    auto alloc = [&](size_t bytes) -> void* {
        o = (o + 255) & ~(size_t)255;
        void* p = ws + o;
        o += bytes;
        return p;
    };
    int nscan = (N + SCHUNK - 1) / SCHUNK;
    int nbk = (N + BW - 1) / BW;
    int*    deg    = (int*)alloc((size_t)N * 4);
    int*    cursor = (int*)alloc((size_t)N * 4);
    int*    off    = (int*)alloc((size_t)(N + 1) * 4);
    int*    nbr    = (int*)alloc((size_t)E * 4);
    float*  dinv   = (float*)alloc((size_t)N * 4);
    float*  aggx   = (float*)alloc((size_t)N * 4);   // fallback only
    float*  yv     = (float*)alloc((size_t)N * 4);   // y = x*dinv (bucket path)
    float*  aggh   = (float*)alloc((size_t)N * F1 * 4);  // fallback only
    double* pooled = (double*)alloc((size_t)G * F2 * 8);
    int*    counts = (int*)alloc((size_t)G * 4);
    int*    starts = (int*)alloc((size_t)(G + 1) * 4);
    int*    partials = (int*)alloc((size_t)nscan * 4);
    int*    bcnt   = (int*)alloc((size_t)nbk * 4);
    int*    bbase  = (int*)alloc((size_t)(nbk + 1) * 4);
    int*    bcur   = (int*)alloc((size_t)nbk * 4);
    float2* aggxd  = (float2*)alloc((size_t)N * 8);
    float*  Mrow   = (float*)alloc((size_t)N * KM * 4);
    float*  Dmat   = (float*)alloc((size_t)KM * F2 * 4);
    double* clbuf  = (double*)alloc((size_t)KM * F1 * 8);
    float*  scal   = (float*)alloc(2 * 4);
    unsigned* amaxb = (unsigned*)alloc(4);
    // gated large buffer: bucketed edge pairs (last)
    o = (o + 255) & ~(size_t)255;
    unsigned long long* pairs = (unsigned long long*)(ws + o);
    bool use_bucket = (o + (size_t)E * 8) <= ws_size;

    hipMemsetAsync(pooled, 0, (size_t)G * F2 * 8, stream);

    int tE = (E + 255) / 256;
    int tN = (N + 255) / 256;
    k_batch_bounds<<<1, 128, 0, stream>>>(batch, N, G, starts, counts);

    if (use_bucket) {
        hipMemsetAsync(bcnt, 0, (size_t)nbk * 4, stream);
        hipMemsetAsync(amaxb, 0, 4, stream);
        k_bucket_count<<<240, 256, nbk * 4, stream>>>(dst, E, nbk, bcnt);
        k_bucket_scan<<<1, 256, 0, stream>>>(bcnt, nbk, E, bbase, bcur);
        k_bucket_scatter<<<240, 256, 0, stream>>>(src, dst, E, nbk, bcur, pairs);
        k_bucket_deg2<<<nbk, 512, 0, stream>>>(pairs, bbase, x, N, dinv, yv);
        k_bucket_aggx<<<nbk, 512, 0, stream>>>(pairs, bbase, yv, dinv, N, aggxd, amaxb);
        k_fit_coef<<<F1, 64, 0, stream>>>(W1, b1, amaxb, clbuf, scal);
        k_fit_fold<<<(KM * F2 + 255) / 256, 256, 0, stream>>>(clbuf, W2, Dmat);
        k_bucket_moments<<<nbk, 512, 0, stream>>>(pairs, bbase, aggxd, scal, N, Mrow);
        k_h2_pool6<<<(N + P6_NODES - 1) / P6_NODES, 256, 0, stream>>>(Mrow, Dmat, b2, batch, N, pooled);
    } else {
        hipMemsetAsync(deg, 0, (size_t)N * 4, stream);
        hipMemsetAsync(cursor, 0, (size_t)N * 4, stream);
        k_count_deg<<<tE, 256, 0, stream>>>(dst, E, deg);
        k_dinv_self<<<tN, 256, 0, stream>>>(deg, x, N, dinv, aggx);
        k_scan_partial<<<nscan, 256, 0, stream>>>(deg, N, partials);
        k_scan_blocks<<<1, 1024, 0, stream>>>(partials, nscan);
        k_scan_final<<<nscan, 256, 0, stream>>>(deg, N, partials, off);
        k_fill_agg<<<tE, 256, 0, stream>>>(src, dst, E, off, cursor, nbr, x, dinv, aggx);
        k_aggh<<<(N + 3) / 4, 256, 0, stream>>>(off, nbr, aggx, dinv, W1, b1, N, aggh);
        k_h2_pool3<<<(N + HP_NODES - 1) / HP_NODES, 256, 0, stream>>>(aggh, W2, b2, batch, N, pooled);
    }
    k_head<<<G, 256, 0, stream>>>(pooled, counts, Wl1, bl1, Wl2, bl2, out);
}

// Round 17
// 166.359 us; speedup vs baseline: 1.9041x; 1.9041x over previous
//
#include <hip/hip_runtime.h>
#include <math.h>

#define F1 100
#define F2 200
#define KM 16          // Chebyshev moments
#define BW_LOG 9
#define BW 512

__device__ __forceinline__ float siluf(float v) {
    return v / (1.0f + expf(-v));   // precise
}
__device__ __forceinline__ float silu_fast(float v) {
    return __fdividef(v, 1.0f + __expf(-v));
}

// batch is sorted: counts via binary-searched boundaries.
__global__ void k_batch_bounds(const int* __restrict__ batch, int N, int G,
                               int* __restrict__ starts, int* __restrict__ counts) {
    int t = threadIdx.x;
    if (t <= G) {
        int lo = 0, hi = N;
        while (lo < hi) {
            int mid = (lo + hi) >> 1;
            if (batch[mid] < t) lo = mid + 1; else hi = mid;
        }
        starts[t] = lo;
    }
    __syncthreads();
    if (t < G) counts[t] = starts[t + 1] - starts[t];
}

// ---- bucketed CSR build ----
__global__ __launch_bounds__(256) void k_bucket_count(const int* __restrict__ dst, int E,
                                                      int nbk, int* __restrict__ gcnt) {
    extern __shared__ int cnt[];
    for (int i = threadIdx.x; i < nbk; i += 256) cnt[i] = 0;
    __syncthreads();
    for (int e = blockIdx.x * 256 + threadIdx.x; e < E; e += gridDim.x * 256)
        atomicAdd(&cnt[dst[e] >> BW_LOG], 1);
    __syncthreads();
    for (int i = threadIdx.x; i < nbk; i += 256)
        if (cnt[i]) atomicAdd(&gcnt[i], cnt[i]);
}

__global__ __launch_bounds__(256) void k_bucket_scan(const int* __restrict__ gcnt, int nbk, int E,
                                                     int* __restrict__ base, int* __restrict__ cursor) {
    __shared__ int sh[256];
    int t = threadIdx.x;
    int v = (t < nbk) ? gcnt[t] : 0;
    sh[t] = v;
    __syncthreads();
    for (int ofs = 1; ofs < 256; ofs <<= 1) {
        int u = (t >= ofs) ? sh[t - ofs] : 0;
        __syncthreads();
        sh[t] += u;
        __syncthreads();
    }
    if (t < nbk) { int ex = sh[t] - v; base[t] = ex; cursor[t] = ex; }
    if (t == 0) base[nbk] = E;
}

#define CROUND 2048
__global__ __launch_bounds__(256) void k_bucket_scatter(
    const int* __restrict__ src, const int* __restrict__ dst, int E, int nbk,
    int* __restrict__ gcursor, unsigned long long* __restrict__ pairs) {
    __shared__ int cnt[256];
    __shared__ int scanb[256];
    __shared__ int startx[256];
    __shared__ int cur[256];
    __shared__ int gbase[256];
    __shared__ unsigned long long stage[CROUND];
    int tid = threadIdx.x;
    for (long long r0 = (long long)blockIdx.x * CROUND; r0 < E; r0 += (long long)gridDim.x * CROUND) {
        cnt[tid] = 0;
        __syncthreads();
        int ss[8], dd[8], bb[8];
        bool va[8];
        #pragma unroll
        for (int j = 0; j < 8; ++j) {
            long long e = r0 + j * 256 + tid;
            va[j] = (e < E);
            if (va[j]) {
                ss[j] = src[e]; dd[j] = dst[e]; bb[j] = dd[j] >> BW_LOG;
                atomicAdd(&cnt[bb[j]], 1);
            }
        }
        __syncthreads();
        scanb[tid] = cnt[tid];
        __syncthreads();
        for (int ofs = 1; ofs < 256; ofs <<= 1) {
            int u = (tid >= ofs) ? scanb[tid - ofs] : 0;
            __syncthreads();
            scanb[tid] += u;
            __syncthreads();
        }
        int ex = scanb[tid] - cnt[tid];
        startx[tid] = ex;
        cur[tid] = ex;
        if (tid < nbk && cnt[tid] > 0) gbase[tid] = atomicAdd(&gcursor[tid], cnt[tid]);
        __syncthreads();
        int total = scanb[255];
        #pragma unroll
        for (int j = 0; j < 8; ++j) {
            if (va[j]) {
                int slot = atomicAdd(&cur[bb[j]], 1);
                stage[slot] = ((unsigned long long)(unsigned)dd[j] << 32) | (unsigned)ss[j];
            }
        }
        __syncthreads();
        for (int i = tid; i < total; i += 256) {
            unsigned long long p = stage[i];
            int b = (int)(p >> 32) >> BW_LOG;
            pairs[gbase[b] + (i - startx[b])] = p;
        }
        __syncthreads();
    }
}

// deg histogram + dinv + y=x*dinv + intra-bucket scan -> global CSR off
__global__ __launch_bounds__(512) void k_bucket_degoff(
    const unsigned long long* __restrict__ pairs, const int* __restrict__ bbase,
    const float* __restrict__ x, int N,
    float* __restrict__ dinv, float* __restrict__ y, int* __restrict__ off) {
    __shared__ int dl[BW];
    __shared__ int sc[BW];
    int b = blockIdx.x;
    int t = threadIdx.x;
    dl[t] = 0;
    __syncthreads();
    int beg = bbase[b], end = bbase[b + 1];
    for (int i = beg + t; i < end; i += 512)
        atomicAdd(&dl[(int)(pairs[i] >> 32) & (BW - 1)], 1);
    __syncthreads();
    int node = (b << BW_LOG) + t;
    int dg = dl[t];
    if (node < N) {
        float d = 1.0f / sqrtf((float)dg + 1.0f);
        dinv[node] = d;
        y[node] = x[node] * d;
    }
    sc[t] = dg;
    __syncthreads();
    for (int ofs = 1; ofs < BW; ofs <<= 1) {
        int u = (t >= ofs) ? sc[t - ofs] : 0;
        __syncthreads();
        sc[t] += u;
        __syncthreads();
    }
    if (node < N) off[node] = beg + sc[t] - dg;
    if (node == N - 1) off[N] = beg + sc[t];
}

// CSR fill (LDS cursors) + layer-1 scalar agg (single random read y[s]) -> aggxd; block-max -> amax.
__global__ __launch_bounds__(512) void k_bucket_fill(
    const unsigned long long* __restrict__ pairs, const int* __restrict__ bbase,
    const int* __restrict__ off, const float* __restrict__ y, const float* __restrict__ dinv,
    int N, int* __restrict__ nbr, float2* __restrict__ aggxd, unsigned* __restrict__ amax) {
    __shared__ int offl[BW];
    __shared__ int cur[BW];
    __shared__ float agg[BW];
    int b = blockIdx.x;
    int t = threadIdx.x;
    int node0 = b << BW_LOG;
    int node = node0 + t;
    offl[t] = (node < N) ? off[node] : 0;
    cur[t] = 0;
    agg[t] = 0.0f;
    __syncthreads();
    int beg = bbase[b], end = bbase[b + 1];
    for (int i = beg + t; i < end; i += 512) {
        unsigned long long p = pairs[i];
        int s = (int)(p & 0xffffffffu);
        int d = (int)(p >> 32);
        int l = d & (BW - 1);
        int pos = atomicAdd(&cur[l], 1);
        nbr[offl[l] + pos] = s;
        atomicAdd(&agg[l], y[s]);
    }
    __syncthreads();
    float av = 0.0f;
    if (node < N) {
        float dn = dinv[node];
        float a = dn * (agg[t] + y[node]);   // y[node] = x*dinv: same value as before
        aggxd[node] = make_float2(a, dn);
        av = fabsf(a);
    }
    __syncthreads();
    agg[t] = av;
    __syncthreads();
    for (int ofs = 256; ofs > 0; ofs >>= 1) {
        if (t < ofs) agg[t] = fmaxf(agg[t], agg[t + ofs]);
        __syncthreads();
    }
    if (t == 0) atomicMax(amax, __float_as_uint(agg[0]));
}

// Fit stage 1: Chebyshev coefficients cl[k][j] of g(a,j)=silu(a*W1[j]+b1[j]) on [-A,A].
__global__ __launch_bounds__(64) void k_fit_coef(
    const float* __restrict__ W1, const float* __restrict__ b1,
    const unsigned* __restrict__ amax_bits,
    double* __restrict__ cl /* [KM][F1] */, float* __restrict__ scal /* {A, invA} */) {
    int j = blockIdx.x;
    int i = threadIdx.x;
    float A = __uint_as_float(*amax_bits);
    if (!(A > 0.0f)) A = 1.0f;
    A *= 1.000001f;
    if (j == 0 && i == 0) { scal[0] = A; scal[1] = 1.0f / A; }
    const double PI = 3.14159265358979323846;
    double th = (i + 0.5) * (PI / 64.0);
    double xx = cos(th);
    double w = (double)W1[j] * (double)A;
    double u = w * xx + (double)b1[j];
    double f = u / (1.0 + exp(-u));
    double acc[KM];
    {
        double c0 = 1.0, c1 = xx;
        acc[0] = f;
        acc[1] = f * xx;
        #pragma unroll
        for (int k = 2; k < KM; ++k) {
            double c2 = 2.0 * xx * c1 - c0;
            acc[k] = f * c2;
            c0 = c1; c1 = c2;
        }
    }
    #pragma unroll
    for (int k = 0; k < KM; ++k) {
        double v = acc[k];
        for (int ofs = 32; ofs > 0; ofs >>= 1)
            v += __shfl_down(v, ofs);
        if (i == 0) cl[k * F1 + j] = v * ((k == 0 ? 1.0 : 2.0) / 64.0);
    }
}

// Fit stage 2: fold through W2: D[k][m] = sum_j cl[k][j] * W2[j][m].
__global__ __launch_bounds__(256) void k_fit_fold(
    const double* __restrict__ cl, const float* __restrict__ W2,
    float* __restrict__ Dmat /* [KM][F2] */) {
    __shared__ double scl[KM * F1];
    int tid = threadIdx.x;
    for (int idx = tid; idx < KM * F1; idx += 256) scl[idx] = cl[idx];
    __syncthreads();
    int idx = blockIdx.x * 256 + tid;
    if (idx >= KM * F2) return;
    int k = idx / F2, m = idx % F2;
    double s = 0.0;
    #pragma unroll 4
    for (int j = 0; j < F1; ++j)
        s += scl[k * F1 + j] * (double)W2[j * F2 + m];
    Dmat[idx] = (float)s;
}

// Moments: M_k(n) = d0^2*T_k(a_n/A) + sum_s dinv_s*d0*T_k(a_s/A). Thread per node (CSR gather).
__global__ __launch_bounds__(256) void k_moments(
    const int* __restrict__ off, const int* __restrict__ nbr,
    const float2* __restrict__ aggxd, const float* __restrict__ scal,
    int N, float* __restrict__ Mrow /* [N][KM] */) {
    int n = blockIdx.x * 256 + threadIdx.x;
    if (n >= N) return;
    float invA = scal[1];
    float2 sd = aggxd[n];
    float d0 = sd.y;
    float m[KM];
    {
        float xa = sd.x * invA;
        float w = d0 * d0;
        float tx = xa + xa;
        float c0 = 1.0f, c1 = xa;
        m[0] = w; m[1] = w * xa;
        #pragma unroll
        for (int k = 2; k < KM; ++k) {
            float c2 = fmaf(tx, c1, -c0);
            m[k] = w * c2;
            c0 = c1; c1 = c2;
        }
    }
    int beg = off[n], end = off[n + 1];
    for (int e = beg; e < end; ++e) {
        int s = nbr[e];
        float2 q = aggxd[s];
        float w = q.y * d0;
        float xa = q.x * invA;
        float tx = xa + xa;
        float c0 = 1.0f, c1 = xa;
        m[0] += w;
        m[1] = fmaf(w, c1, m[1]);
        #pragma unroll
        for (int k = 2; k < KM; ++k) {
            float c2 = fmaf(tx, c1, -c0);
            m[k] = fmaf(w, c2, m[k]);
            c0 = c1; c1 = c2;
        }
    }
    float4* out4 = (float4*)(Mrow + (size_t)n * KM);
    out4[0] = make_float4(m[0], m[1], m[2], m[3]);
    out4[1] = make_float4(m[4], m[5], m[6], m[7]);
    out4[2] = make_float4(m[8], m[9], m[10], m[11]);
    out4[3] = make_float4(m[12], m[13], m[14], m[15]);
}

// Fused h2 = silu(M @ D + b2) + graph mean-pool numerator (2-node ILP unroll).
#define P6_NODES 32
__global__ __launch_bounds__(256) void k_h2_pool6(
    const float* __restrict__ Mrow, const float* __restrict__ Dmat,
    const float* __restrict__ b2, const int* __restrict__ batch,
    int N, double* __restrict__ pooled) {
    __shared__ float sM[P6_NODES][KM];   // 2 KB
    __shared__ int sbatch[P6_NODES];
    int tid = threadIdx.x;
    int base = blockIdx.x * P6_NODES;
    if (tid < P6_NODES * 4) {
        int node = tid >> 2, q = tid & 3;
        float4 v = make_float4(0.f, 0.f, 0.f, 0.f);
        if (base + node < N)
            v = ((const float4*)(Mrow + (size_t)(base + node) * KM))[q];
        ((float4*)&sM[node][0])[q] = v;
    }
    if (tid < P6_NODES) {
        int n = base + tid;
        sbatch[tid] = (n < N) ? batch[n] : -1;
    }
    int m = tid;
    bool act = (m < F2);
    float4 d4[KM / 4];
    float bb = 0.0f;
    if (act) {
        #pragma unroll
        for (int k = 0; k < KM / 4; ++k) {
            d4[k].x = Dmat[(4 * k + 0) * F2 + m];
            d4[k].y = Dmat[(4 * k + 1) * F2 + m];
            d4[k].z = Dmat[(4 * k + 2) * F2 + m];
            d4[k].w = Dmat[(4 * k + 3) * F2 + m];
        }
        bb = b2[m];
    }
    __syncthreads();
    double pl = 0.0;
    int gcur = -1;
    int nlim = min(P6_NODES, N - base);
    int i = 0;
    for (; i + 1 < nlim; i += 2) {
        float preA, preB;
        {
            const float4* mA = (const float4*)&sM[i][0];
            const float4* mB = (const float4*)&sM[i + 1][0];
            float4 a0 = mA[0], a1 = mA[1], a2 = mA[2], a3 = mA[3];
            float4 c0 = mB[0], c1 = mB[1], c2 = mB[2], c3 = mB[3];
            float p0 = bb, p1 = 0.f, p2 = 0.f, p3 = 0.f;
            float q0 = bb, q1 = 0.f, q2 = 0.f, q3 = 0.f;
            p0 = fmaf(a0.x, d4[0].x, p0); q0 = fmaf(c0.x, d4[0].x, q0);
            p1 = fmaf(a0.y, d4[0].y, p1); q1 = fmaf(c0.y, d4[0].y, q1);
            p2 = fmaf(a0.z, d4[0].z, p2); q2 = fmaf(c0.z, d4[0].z, q2);
            p3 = fmaf(a0.w, d4[0].w, p3); q3 = fmaf(c0.w, d4[0].w, q3);
            p0 = fmaf(a1.x, d4[1].x, p0); q0 = fmaf(c1.x, d4[1].x, q0);
            p1 = fmaf(a1.y, d4[1].y, p1); q1 = fmaf(c1.y, d4[1].y, q1);
            p2 = fmaf(a1.z, d4[1].z, p2); q2 = fmaf(c1.z, d4[1].z, q2);
            p3 = fmaf(a1.w, d4[1].w, p3); q3 = fmaf(c1.w, d4[1].w, q3);
            p0 = fmaf(a2.x, d4[2].x, p0); q0 = fmaf(c2.x, d4[2].x, q0);
            p1 = fmaf(a2.y, d4[2].y, p1); q1 = fmaf(c2.y, d4[2].y, q1);
            p2 = fmaf(a2.z, d4[2].z, p2); q2 = fmaf(c2.z, d4[2].z, q2);
            p3 = fmaf(a2.w, d4[2].w, p3); q3 = fmaf(c2.w, d4[2].w, q3);
            p0 = fmaf(a3.x, d4[3].x, p0); q0 = fmaf(c3.x, d4[3].x, q0);
            p1 = fmaf(a3.y, d4[3].y, p1); q1 = fmaf(c3.y, d4[3].y, q1);
            p2 = fmaf(a3.z, d4[3].z, p2); q2 = fmaf(c3.z, d4[3].z, q2);
            p3 = fmaf(a3.w, d4[3].w, p3); q3 = fmaf(c3.w, d4[3].w, q3);
            preA = (p0 + p1) + (p2 + p3);
            preB = (q0 + q1) + (q2 + q3);
        }
        float hA = silu_fast(preA);
        float hB = silu_fast(preB);
        int g = sbatch[i];
        if (g != gcur) {
            if (gcur >= 0 && act) atomicAdd(&pooled[(size_t)gcur * F2 + m], pl);
            pl = 0.0;
            gcur = g;
        }
        if (act) pl += (double)hA;
        g = sbatch[i + 1];
        if (g != gcur) {
            if (gcur >= 0 && act) atomicAdd(&pooled[(size_t)gcur * F2 + m], pl);
            pl = 0.0;
            gcur = g;
        }
        if (act) pl += (double)hB;
    }
    if (i < nlim) {
        const float4* m4 = (const float4*)&sM[i][0];
        float4 a0 = m4[0], a1 = m4[1], a2 = m4[2], a3 = m4[3];
        float p0 = bb, p1 = 0.f, p2 = 0.f, p3 = 0.f;
        p0 = fmaf(a0.x, d4[0].x, p0); p1 = fmaf(a0.y, d4[0].y, p1);
        p2 = fmaf(a0.z, d4[0].z, p2); p3 = fmaf(a0.w, d4[0].w, p3);
        p0 = fmaf(a1.x, d4[1].x, p0); p1 = fmaf(a1.y, d4[1].y, p1);
        p2 = fmaf(a1.z, d4[1].z, p2); p3 = fmaf(a1.w, d4[1].w, p3);
        p0 = fmaf(a2.x, d4[2].x, p0); p1 = fmaf(a2.y, d4[2].y, p1);
        p2 = fmaf(a2.z, d4[2].z, p2); p3 = fmaf(a2.w, d4[2].w, p3);
        p0 = fmaf(a3.x, d4[3].x, p0); p1 = fmaf(a3.y, d4[3].y, p1);
        p2 = fmaf(a3.z, d4[3].z, p2); p3 = fmaf(a3.w, d4[3].w, p3);
        float pre = (p0 + p1) + (p2 + p3);
        int g = sbatch[i];
        if (g != gcur) {
            if (gcur >= 0 && act) atomicAdd(&pooled[(size_t)gcur * F2 + m], pl);
            pl = 0.0;
            gcur = g;
        }
        if (act) pl += (double)silu_fast(pre);
    }
    if (gcur >= 0 && act) atomicAdd(&pooled[(size_t)gcur * F2 + m], pl);
}

// ---- fallback path kernels (ws too small for pairs) ----
#define SCHUNK 2048
__global__ __launch_bounds__(256) void k_scan_partial(const int* __restrict__ deg, int N,
                                                      int* __restrict__ partials) {
    __shared__ int red[256];
    int base = blockIdx.x * SCHUNK;
    int s = 0;
    for (int i = threadIdx.x; i < SCHUNK; i += 256) {
        int idx = base + i;
        if (idx < N) s += deg[idx];
    }
    red[threadIdx.x] = s;
    __syncthreads();
    for (int ofs = 128; ofs > 0; ofs >>= 1) {
        if (threadIdx.x < ofs) red[threadIdx.x] += red[threadIdx.x + ofs];
        __syncthreads();
    }
    if (threadIdx.x == 0) partials[blockIdx.x] = red[0];
}
__global__ __launch_bounds__(1024) void k_scan_blocks(int* __restrict__ partials, int nb) {
    __shared__ int sh[1024];
    int t = threadIdx.x;
    int v = (t < nb) ? partials[t] : 0;
    sh[t] = v;
    __syncthreads();
    for (int ofs = 1; ofs < 1024; ofs <<= 1) {
        int u = (t >= ofs) ? sh[t - ofs] : 0;
        __syncthreads();
        sh[t] += u;
        __syncthreads();
    }
    if (t < nb) partials[t] = sh[t] - v;
}
__global__ __launch_bounds__(256) void k_scan_final(const int* __restrict__ deg, int N,
                                                    const int* __restrict__ partials,
                                                    int* __restrict__ off) {
    __shared__ int sh[256];
    int base = blockIdx.x * SCHUNK;
    int i0 = base + threadIdx.x * 8;
    int v[8];
    int s = 0;
    #pragma unroll
    for (int j = 0; j < 8; ++j) {
        int idx = i0 + j;
        v[j] = (idx < N) ? deg[idx] : 0;
        s += v[j];
    }
    int mine = s;
    sh[threadIdx.x] = s;
    __syncthreads();
    for (int ofs = 1; ofs < 256; ofs <<= 1) {
        int u = (threadIdx.x >= ofs) ? sh[threadIdx.x - ofs] : 0;
        __syncthreads();
        sh[threadIdx.x] += u;
        __syncthreads();
    }
    int run = partials[blockIdx.x] + sh[threadIdx.x] - mine;
    #pragma unroll
    for (int j = 0; j < 8; ++j) {
        int idx = i0 + j;
        if (idx < N) { off[idx] = run; run += v[j]; }
    }
    if (N >= i0 && N <= i0 + 8) off[N] = run;
}
__global__ void k_count_deg(const int* __restrict__ dst, int E, int* __restrict__ deg) {
    int i = blockIdx.x * blockDim.x + threadIdx.x;
    if (i < E) atomicAdd(&deg[dst[i]], 1);
}
__global__ void k_dinv_self(const int* __restrict__ deg, const float* __restrict__ x, int N,
                            float* __restrict__ dinv, float* __restrict__ aggx) {
    int i = blockIdx.x * blockDim.x + threadIdx.x;
    if (i < N) {
        float d = 1.0f / sqrtf((float)deg[i] + 1.0f);
        dinv[i] = d;
        aggx[i] = x[i] * d * d;
    }
}
__global__ void k_fill_agg(const int* __restrict__ src, const int* __restrict__ dst, int E,
                           const int* __restrict__ off, int* __restrict__ cursor,
                           int* __restrict__ nbr,
                           const float* __restrict__ x, const float* __restrict__ dinv,
                           float* __restrict__ aggx) {
    int e = blockIdx.x * blockDim.x + threadIdx.x;
    if (e < E) {
        int s = src[e], d = dst[e];
        int p = atomicAdd(&cursor[d], 1);
        nbr[off[d] + p] = s;
        atomicAdd(&aggx[d], x[s] * dinv[s] * dinv[d]);
    }
}
__global__ __launch_bounds__(256) void k_aggh(
    const int* __restrict__ off, const int* __restrict__ nbr,
    const float* __restrict__ aggx, const float* __restrict__ dinv,
    const float* __restrict__ W1, const float* __restrict__ b1,
    int N, float* __restrict__ aggh) {
    int wave = threadIdx.x >> 6;
    int lane = threadIdx.x & 63;
    int n = blockIdx.x * 4 + wave;
    if (n >= N) return;
    int ja = lane, jb = lane + 64;
    float w1a = (ja < F1) ? W1[ja] : 0.0f;
    float b1a = (ja < F1) ? b1[ja] : 0.0f;
    float w1b = (jb < F1) ? W1[jb] : 0.0f;
    float b1b = (jb < F1) ? b1[jb] : 0.0f;
    float d0 = dinv[n];
    float a0 = aggx[n];
    float accA = silu_fast(fmaf(a0, w1a, b1a)) * (d0 * d0);
    float accB = silu_fast(fmaf(a0, w1b, b1b)) * (d0 * d0);
    int beg = off[n], end = off[n + 1];
    for (int t = beg; t < end; t += 64) {
        int cnt = min(64, end - t);
        float sa = 0.0f, sw = 0.0f;
        if (lane < cnt) {
            int s = nbr[t + lane];
            sa = aggx[s];
            sw = dinv[s] * d0;
        }
        for (int i = 0; i < cnt; ++i) {
            float ai = __shfl(sa, i);
            float wi = __shfl(sw, i);
            accA = fmaf(wi, silu_fast(fmaf(ai, w1a, b1a)), accA);
            accB = fmaf(wi, silu_fast(fmaf(ai, w1b, b1b)), accB);
        }
    }
    if (ja < F1) aggh[(size_t)n * F1 + ja] = accA;
    if (jb < F1) aggh[(size_t)n * F1 + jb] = accB;
}
#define HP_NODES 20
#define HP_KT 25
__global__ __launch_bounds__(256) void k_h2_pool3(
    const float* __restrict__ aggh, const float* __restrict__ W2, const float* __restrict__ b2,
    const int* __restrict__ batch, int N, double* __restrict__ pooled) {
    __shared__ float smem[HP_KT * F2 + HP_NODES * (F1 + 1)];
    float* sW = smem;
    float* sA = smem + HP_KT * F2;
    float* sOut = smem;
    __shared__ int sbatch[HP_NODES];
    int tid = threadIdx.x;
    int base = blockIdx.x * HP_NODES;
    for (int idx = tid; idx < HP_NODES * (F1 / 4); idx += 256) {
        int i = idx / (F1 / 4), q = idx % (F1 / 4);
        int n = base + i;
        float4 v = make_float4(0.f, 0.f, 0.f, 0.f);
        if (n < N) v = *(const float4*)(aggh + (size_t)n * F1 + q * 4);
        float* dp = &sA[i * (F1 + 1) + q * 4];
        dp[0] = v.x; dp[1] = v.y; dp[2] = v.z; dp[3] = v.w;
    }
    if (tid < HP_NODES) {
        int n = base + tid;
        sbatch[tid] = (n < N) ? batch[n] : -1;
    }
    const int fgrp = tid % 50;
    const int ngrp = tid / 50;
    const int m0 = fgrp * 4;
    const int i0 = ngrp * 4;
    const bool act = (tid < 250);
    float acc[4][4];
    #pragma unroll
    for (int i = 0; i < 4; ++i)
        #pragma unroll
        for (int j = 0; j < 4; ++j) acc[i][j] = 0.0f;
    for (int kt = 0; kt < F1; kt += HP_KT) {
        __syncthreads();
        for (int idx = tid; idx < (HP_KT * F2) / 4; idx += 256)
            ((float4*)sW)[idx] = ((const float4*)(W2 + (size_t)kt * F2))[idx];
        __syncthreads();
        if (act) {
            #pragma unroll
            for (int kk = 0; kk < HP_KT; ++kk) {
                float4 w = *(const float4*)&sW[kk * F2 + m0];
                int k = kt + kk;
                float a0 = sA[(i0 + 0) * (F1 + 1) + k];
                float a1 = sA[(i0 + 1) * (F1 + 1) + k];
                float a2 = sA[(i0 + 2) * (F1 + 1) + k];
                float a3 = sA[(i0 + 3) * (F1 + 1) + k];
                acc[0][0] = fmaf(a0, w.x, acc[0][0]); acc[0][1] = fmaf(a0, w.y, acc[0][1]);
                acc[0][2] = fmaf(a0, w.z, acc[0][2]); acc[0][3] = fmaf(a0, w.w, acc[0][3]);
                acc[1][0] = fmaf(a1, w.x, acc[1][0]); acc[1][1] = fmaf(a1, w.y, acc[1][1]);
                acc[1][2] = fmaf(a1, w.z, acc[1][2]); acc[1][3] = fmaf(a1, w.w, acc[1][3]);
                acc[2][0] = fmaf(a2, w.x, acc[2][0]); acc[2][1] = fmaf(a2, w.y, acc[2][1]);
                acc[2][2] = fmaf(a2, w.z, acc[2][2]); acc[2][3] = fmaf(a2, w.w, acc[2][3]);
                acc[3][0] = fmaf(a3, w.x, acc[3][0]); acc[3][1] = fmaf(a3, w.y, acc[3][1]);
                acc[3][2] = fmaf(a3, w.z, acc[3][2]); acc[3][3] = fmaf(a3, w.w, acc[3][3]);
            }
        }
    }
    __syncthreads();
    if (act) {
        float4 bb = *(const float4*)(b2 + m0);
        #pragma unroll
        for (int i = 0; i < 4; ++i) {
            float4 r;
            r.x = siluf(acc[i][0] + bb.x);
            r.y = siluf(acc[i][1] + bb.y);
            r.z = siluf(acc[i][2] + bb.z);
            r.w = siluf(acc[i][3] + bb.w);
            *(float4*)&sOut[(i0 + i) * F2 + m0] = r;
        }
    }
    __syncthreads();
    if (tid < F2) {
        double pl = 0.0;
        int gcur = -1;
        for (int i = 0; i < HP_NODES; ++i) {
            int n = base + i;
            if (n >= N) break;
            int g = sbatch[i];
            if (g != gcur) {
                if (gcur >= 0) atomicAdd(&pooled[(size_t)gcur * F2 + tid], pl);
                pl = 0.0;
                gcur = g;
            }
            pl += (double)sOut[i * F2 + tid];
        }
        if (gcur >= 0) atomicAdd(&pooled[(size_t)gcur * F2 + tid], pl);
    }
}

// Head MLP: one block per graph, double precision.
__global__ __launch_bounds__(256) void k_head(
    const double* __restrict__ pooled, const int* __restrict__ counts,
    const float* __restrict__ Wl1, const float* __restrict__ bl1,
    const float* __restrict__ Wl2, const float* __restrict__ bl2,
    float* __restrict__ out) {
    int g = blockIdx.x;
    int tid = threadIdx.x;
    __shared__ double sp[F2];
    __shared__ double red[256];
    double icnt = 1.0 / (double)max(counts[g], 1);
    for (int m = tid; m < F2; m += 256) sp[m] = pooled[(size_t)g * F2 + m] * icnt;
    __syncthreads();
    double part = 0.0;
    if (tid < 100) {
        double acc = (double)bl1[tid];
        #pragma unroll 4
        for (int m = 0; m < F2; ++m) acc += sp[m] * (double)Wl1[m * 100 + tid];
        double t1 = acc / (1.0 + exp(-acc));
        part = t1 * (double)Wl2[tid];
    }
    red[tid] = part;
    __syncthreads();
    for (int s = 128; s > 0; s >>= 1) {
        if (tid < s) red[tid] += red[tid + s];
        __syncthreads();
    }
    if (tid == 0) out[g] = (float)(red[0] + (double)bl2[0]);
}

extern "C" void kernel_launch(void* const* d_in, const int* in_sizes, int n_in,
                              void* d_out, int out_size, void* d_ws, size_t ws_size,
                              hipStream_t stream)
{
    const float* x   = (const float*)d_in[0];
    const int*   src = (const int*)d_in[1];
    const int*   dst = (const int*)d_in[2];
    const int*   batch = (const int*)d_in[3];
    const float* W1  = (const float*)d_in[4];
    const float* b1  = (const float*)d_in[5];
    const float* W2  = (const float*)d_in[6];
    const float* b2  = (const float*)d_in[7];
    const float* Wl1 = (const float*)d_in[8];
    const float* bl1 = (const float*)d_in[9];
    const float* Wl2 = (const float*)d_in[10];
    const float* bl2 = (const float*)d_in[11];
    int N = in_sizes[0];
    int E = in_sizes[1];
    int G = out_size;
    float* out = (float*)d_out;

    char* ws = (char*)d_ws;
    size_t o = 0;
    auto alloc = [&](size_t bytes) -> void* {
        o = (o + 255) & ~(size_t)255;
        void* p = ws + o;
        o += bytes;
        return p;
    };
    int nscan = (N + SCHUNK - 1) / SCHUNK;
    int nbk = (N + BW - 1) / BW;
    int*    deg    = (int*)alloc((size_t)N * 4);
    int*    cursor = (int*)alloc((size_t)N * 4);
    int*    off    = (int*)alloc((size_t)(N + 1) * 4);
    int*    nbr    = (int*)alloc((size_t)E * 4);
    float*  dinv   = (float*)alloc((size_t)N * 4);
    float*  aggx   = (float*)alloc((size_t)N * 4);   // fallback only
    float*  yv     = (float*)alloc((size_t)N * 4);   // y = x*dinv (bucket path)
    float*  aggh   = (float*)alloc((size_t)N * F1 * 4);  // fallback only
    double* pooled = (double*)alloc((size_t)G * F2 * 8);
    int*    counts = (int*)alloc((size_t)G * 4);
    int*    starts = (int*)alloc((size_t)(G + 1) * 4);
    int*    partials = (int*)alloc((size_t)nscan * 4);
    int*    bcnt   = (int*)alloc((size_t)nbk * 4);
    int*    bbase  = (int*)alloc((size_t)(nbk + 1) * 4);
    int*    bcur   = (int*)alloc((size_t)nbk * 4);
    float2* aggxd  = (float2*)alloc((size_t)N * 8);
    float*  Mrow   = (float*)alloc((size_t)N * KM * 4);
    float*  Dmat   = (float*)alloc((size_t)KM * F2 * 4);
    double* clbuf  = (double*)alloc((size_t)KM * F1 * 8);
    float*  scal   = (float*)alloc(2 * 4);
    unsigned* amaxb = (unsigned*)alloc(4);
    // gated large buffer: bucketed edge pairs (last)
    o = (o + 255) & ~(size_t)255;
    unsigned long long* pairs = (unsigned long long*)(ws + o);
    bool use_bucket = (o + (size_t)E * 8) <= ws_size;

    hipMemsetAsync(pooled, 0, (size_t)G * F2 * 8, stream);

    int tE = (E + 255) / 256;
    int tN = (N + 255) / 256;
    k_batch_bounds<<<1, 128, 0, stream>>>(batch, N, G, starts, counts);

    if (use_bucket) {
        hipMemsetAsync(bcnt, 0, (size_t)nbk * 4, stream);
        hipMemsetAsync(amaxb, 0, 4, stream);
        k_bucket_count<<<240, 256, nbk * 4, stream>>>(dst, E, nbk, bcnt);
        k_bucket_scan<<<1, 256, 0, stream>>>(bcnt, nbk, E, bbase, bcur);
        k_bucket_scatter<<<240, 256, 0, stream>>>(src, dst, E, nbk, bcur, pairs);
        k_bucket_degoff<<<nbk, 512, 0, stream>>>(pairs, bbase, x, N, dinv, yv, off);
        k_bucket_fill<<<nbk, 512, 0, stream>>>(pairs, bbase, off, yv, dinv, N, nbr, aggxd, amaxb);
        k_fit_coef<<<F1, 64, 0, stream>>>(W1, b1, amaxb, clbuf, scal);
        k_fit_fold<<<(KM * F2 + 255) / 256, 256, 0, stream>>>(clbuf, W2, Dmat);
        k_moments<<<(N + 255) / 256, 256, 0, stream>>>(off, nbr, aggxd, scal, N, Mrow);
        k_h2_pool6<<<(N + P6_NODES - 1) / P6_NODES, 256, 0, stream>>>(Mrow, Dmat, b2, batch, N, pooled);
    } else {
        hipMemsetAsync(deg, 0, (size_t)N * 4, stream);
        hipMemsetAsync(cursor, 0, (size_t)N * 4, stream);
        k_count_deg<<<tE, 256, 0, stream>>>(dst, E, deg);
        k_dinv_self<<<tN, 256, 0, stream>>>(deg, x, N, dinv, aggx);
        k_scan_partial<<<nscan, 256, 0, stream>>>(deg, N, partials);
        k_scan_blocks<<<1, 1024, 0, stream>>>(partials, nscan);
        k_scan_final<<<nscan, 256, 0, stream>>>(deg, N, partials, off);
        k_fill_agg<<<tE, 256, 0, stream>>>(src, dst, E, off, cursor, nbr, x, dinv, aggx);
        k_aggh<<<(N + 3) / 4, 256, 0, stream>>>(off, nbr, aggx, dinv, W1, b1, N, aggh);
        k_h2_pool3<<<(N + HP_NODES - 1) / HP_NODES, 256, 0, stream>>>(aggh, W2, b2, batch, N, pooled);
    }
    k_head<<<G, 256, 0, stream>>>(pooled, counts, Wl1, bl1, Wl2, bl2, out);
}

// Round 18
// 154.523 us; speedup vs baseline: 2.0500x; 1.0766x over previous
//
#include <hip/hip_runtime.h>
#include <math.h>

#define F1 100
#define F2 200
#define KM 16          // Chebyshev moments
#define BW_LOG 9
#define BW 512

__device__ __forceinline__ float siluf(float v) {
    return v / (1.0f + expf(-v));   // precise
}
__device__ __forceinline__ float silu_fast(float v) {
    return __fdividef(v, 1.0f + __expf(-v));
}

// Fused prologue: batch bounds (block 0) + zero pooled (all blocks) + zero bcnt/amax (block 1).
#define PREP_BLOCKS 16
__global__ __launch_bounds__(256) void k_prep(
    const int* __restrict__ batch, int N, int G, int nbk,
    int* __restrict__ starts, int* __restrict__ counts,
    double* __restrict__ pooled, int* __restrict__ bcnt, unsigned* __restrict__ amax) {
    int t = threadIdx.x;
    int b = blockIdx.x;
    // zero pooled: G*F2 doubles, grid-strided
    for (int idx = b * 256 + t; idx < G * F2; idx += PREP_BLOCKS * 256)
        pooled[idx] = 0.0;
    if (b == 1) {
        for (int i = t; i < nbk; i += 256) bcnt[i] = 0;
        if (t == 0) *amax = 0u;
    }
    if (b == 0) {
        if (t <= G) {
            int lo = 0, hi = N;
            while (lo < hi) {
                int mid = (lo + hi) >> 1;
                if (batch[mid] < t) lo = mid + 1; else hi = mid;
            }
            starts[t] = lo;
        }
        __syncthreads();
        if (t < G) counts[t] = starts[t + 1] - starts[t];
    }
}

// ---- bucketed CSR build ----
__global__ __launch_bounds__(256) void k_bucket_count(const int* __restrict__ dst, int E,
                                                      int nbk, int* __restrict__ gcnt) {
    extern __shared__ int cnt[];
    for (int i = threadIdx.x; i < nbk; i += 256) cnt[i] = 0;
    __syncthreads();
    for (int e = blockIdx.x * 256 + threadIdx.x; e < E; e += gridDim.x * 256)
        atomicAdd(&cnt[dst[e] >> BW_LOG], 1);
    __syncthreads();
    for (int i = threadIdx.x; i < nbk; i += 256)
        if (cnt[i]) atomicAdd(&gcnt[i], cnt[i]);
}

__global__ __launch_bounds__(256) void k_bucket_scan(const int* __restrict__ gcnt, int nbk, int E,
                                                     int* __restrict__ base, int* __restrict__ cursor) {
    __shared__ int sh[256];
    int t = threadIdx.x;
    int v = (t < nbk) ? gcnt[t] : 0;
    sh[t] = v;
    __syncthreads();
    for (int ofs = 1; ofs < 256; ofs <<= 1) {
        int u = (t >= ofs) ? sh[t - ofs] : 0;
        __syncthreads();
        sh[t] += u;
        __syncthreads();
    }
    if (t < nbk) { int ex = sh[t] - v; base[t] = ex; cursor[t] = ex; }
    if (t == 0) base[nbk] = E;
}

// 4096-edge rounds: half the scan/barrier overhead of 2048 (R17).
#define CROUND 4096
#define CEPT 16   // edges per thread per round
__global__ __launch_bounds__(256) void k_bucket_scatter(
    const int* __restrict__ src, const int* __restrict__ dst, int E, int nbk,
    int* __restrict__ gcursor, unsigned long long* __restrict__ pairs) {
    __shared__ int cnt[256];
    __shared__ int scanb[256];
    __shared__ int startx[256];
    __shared__ int cur[256];
    __shared__ int gbase[256];
    __shared__ unsigned long long stage[CROUND];
    int tid = threadIdx.x;
    for (long long r0 = (long long)blockIdx.x * CROUND; r0 < E; r0 += (long long)gridDim.x * CROUND) {
        cnt[tid] = 0;
        __syncthreads();
        int ss[CEPT], dd[CEPT], bb[CEPT];
        bool va[CEPT];
        #pragma unroll
        for (int j = 0; j < CEPT; ++j) {
            long long e = r0 + j * 256 + tid;
            va[j] = (e < E);
            if (va[j]) {
                ss[j] = src[e]; dd[j] = dst[e]; bb[j] = dd[j] >> BW_LOG;
                atomicAdd(&cnt[bb[j]], 1);
            }
        }
        __syncthreads();
        scanb[tid] = cnt[tid];
        __syncthreads();
        for (int ofs = 1; ofs < 256; ofs <<= 1) {
            int u = (tid >= ofs) ? scanb[tid - ofs] : 0;
            __syncthreads();
            scanb[tid] += u;
            __syncthreads();
        }
        int ex = scanb[tid] - cnt[tid];
        startx[tid] = ex;
        cur[tid] = ex;
        if (tid < nbk && cnt[tid] > 0) gbase[tid] = atomicAdd(&gcursor[tid], cnt[tid]);
        __syncthreads();
        int total = scanb[255];
        #pragma unroll
        for (int j = 0; j < CEPT; ++j) {
            if (va[j]) {
                int slot = atomicAdd(&cur[bb[j]], 1);
                stage[slot] = ((unsigned long long)(unsigned)dd[j] << 32) | (unsigned)ss[j];
            }
        }
        __syncthreads();
        for (int i = tid; i < total; i += 256) {
            unsigned long long p = stage[i];
            int b = (int)(p >> 32) >> BW_LOG;
            pairs[gbase[b] + (i - startx[b])] = p;
        }
        __syncthreads();
    }
}

// deg histogram + dinv + y=x*dinv + intra-bucket scan -> global CSR off
__global__ __launch_bounds__(512) void k_bucket_degoff(
    const unsigned long long* __restrict__ pairs, const int* __restrict__ bbase,
    const float* __restrict__ x, int N,
    float* __restrict__ dinv, float* __restrict__ y, int* __restrict__ off) {
    __shared__ int dl[BW];
    __shared__ int sc[BW];
    int b = blockIdx.x;
    int t = threadIdx.x;
    dl[t] = 0;
    __syncthreads();
    int beg = bbase[b], end = bbase[b + 1];
    for (int i = beg + t; i < end; i += 512)
        atomicAdd(&dl[(int)(pairs[i] >> 32) & (BW - 1)], 1);
    __syncthreads();
    int node = (b << BW_LOG) + t;
    int dg = dl[t];
    if (node < N) {
        float d = 1.0f / sqrtf((float)dg + 1.0f);
        dinv[node] = d;
        y[node] = x[node] * d;
    }
    sc[t] = dg;
    __syncthreads();
    for (int ofs = 1; ofs < BW; ofs <<= 1) {
        int u = (t >= ofs) ? sc[t - ofs] : 0;
        __syncthreads();
        sc[t] += u;
        __syncthreads();
    }
    if (node < N) off[node] = beg + sc[t] - dg;
    if (node == N - 1) off[N] = beg + sc[t];
}

// CSR fill (LDS cursors) + layer-1 scalar agg (single random read y[s]) -> aggxd; block-max -> amax.
__global__ __launch_bounds__(512) void k_bucket_fill(
    const unsigned long long* __restrict__ pairs, const int* __restrict__ bbase,
    const int* __restrict__ off, const float* __restrict__ y, const float* __restrict__ dinv,
    int N, int* __restrict__ nbr, float2* __restrict__ aggxd, unsigned* __restrict__ amax) {
    __shared__ int offl[BW];
    __shared__ int cur[BW];
    __shared__ float agg[BW];
    int b = blockIdx.x;
    int t = threadIdx.x;
    int node0 = b << BW_LOG;
    int node = node0 + t;
    offl[t] = (node < N) ? off[node] : 0;
    cur[t] = 0;
    agg[t] = 0.0f;
    __syncthreads();
    int beg = bbase[b], end = bbase[b + 1];
    for (int i = beg + t; i < end; i += 512) {
        unsigned long long p = pairs[i];
        int s = (int)(p & 0xffffffffu);
        int d = (int)(p >> 32);
        int l = d & (BW - 1);
        int pos = atomicAdd(&cur[l], 1);
        nbr[offl[l] + pos] = s;
        atomicAdd(&agg[l], y[s]);
    }
    __syncthreads();
    float av = 0.0f;
    if (node < N) {
        float dn = dinv[node];
        float a = dn * (agg[t] + y[node]);
        aggxd[node] = make_float2(a, dn);
        av = fabsf(a);
    }
    __syncthreads();
    agg[t] = av;
    __syncthreads();
    for (int ofs = 256; ofs > 0; ofs >>= 1) {
        if (t < ofs) agg[t] = fmaxf(agg[t], agg[t + ofs]);
        __syncthreads();
    }
    if (t == 0) atomicMax(amax, __float_as_uint(agg[0]));
}

// Fit stage 1: Chebyshev coefficients cl[k][j] of g(a,j)=silu(a*W1[j]+b1[j]) on [-A,A].
__global__ __launch_bounds__(64) void k_fit_coef(
    const float* __restrict__ W1, const float* __restrict__ b1,
    const unsigned* __restrict__ amax_bits,
    double* __restrict__ cl /* [KM][F1] */, float* __restrict__ scal /* {A, invA} */) {
    int j = blockIdx.x;
    int i = threadIdx.x;
    float A = __uint_as_float(*amax_bits);
    if (!(A > 0.0f)) A = 1.0f;
    A *= 1.000001f;
    if (j == 0 && i == 0) { scal[0] = A; scal[1] = 1.0f / A; }
    const double PI = 3.14159265358979323846;
    double th = (i + 0.5) * (PI / 64.0);
    double xx = cos(th);
    double w = (double)W1[j] * (double)A;
    double u = w * xx + (double)b1[j];
    double f = u / (1.0 + exp(-u));
    double acc[KM];
    {
        double c0 = 1.0, c1 = xx;
        acc[0] = f;
        acc[1] = f * xx;
        #pragma unroll
        for (int k = 2; k < KM; ++k) {
            double c2 = 2.0 * xx * c1 - c0;
            acc[k] = f * c2;
            c0 = c1; c1 = c2;
        }
    }
    #pragma unroll
    for (int k = 0; k < KM; ++k) {
        double v = acc[k];
        for (int ofs = 32; ofs > 0; ofs >>= 1)
            v += __shfl_down(v, ofs);
        if (i == 0) cl[k * F1 + j] = v * ((k == 0 ? 1.0 : 2.0) / 64.0);
    }
}

// Fit stage 2: fold through W2: D[k][m] = sum_j cl[k][j] * W2[j][m].
__global__ __launch_bounds__(256) void k_fit_fold(
    const double* __restrict__ cl, const float* __restrict__ W2,
    float* __restrict__ Dmat /* [KM][F2] */) {
    __shared__ double scl[KM * F1];
    int tid = threadIdx.x;
    for (int idx = tid; idx < KM * F1; idx += 256) scl[idx] = cl[idx];
    __syncthreads();
    int idx = blockIdx.x * 256 + tid;
    if (idx >= KM * F2) return;
    int k = idx / F2, m = idx % F2;
    double s = 0.0;
    #pragma unroll 4
    for (int j = 0; j < F1; ++j)
        s += scl[k * F1 + j] * (double)W2[j * F2 + m];
    Dmat[idx] = (float)s;
}

// Moments: M_k(n) = d0^2*T_k(a_n/A) + sum_s dinv_s*d0*T_k(a_s/A). Thread per node (CSR gather).
__global__ __launch_bounds__(256) void k_moments(
    const int* __restrict__ off, const int* __restrict__ nbr,
    const float2* __restrict__ aggxd, const float* __restrict__ scal,
    int N, float* __restrict__ Mrow /* [N][KM] */) {
    int n = blockIdx.x * 256 + threadIdx.x;
    if (n >= N) return;
    float invA = scal[1];
    float2 sd = aggxd[n];
    float d0 = sd.y;
    float m[KM];
    {
        float xa = sd.x * invA;
        float w = d0 * d0;
        float tx = xa + xa;
        float c0 = 1.0f, c1 = xa;
        m[0] = w; m[1] = w * xa;
        #pragma unroll
        for (int k = 2; k < KM; ++k) {
            float c2 = fmaf(tx, c1, -c0);
            m[k] = w * c2;
            c0 = c1; c1 = c2;
        }
    }
    int beg = off[n], end = off[n + 1];
    for (int e = beg; e < end; ++e) {
        int s = nbr[e];
        float2 q = aggxd[s];
        float w = q.y * d0;
        float xa = q.x * invA;
        float tx = xa + xa;
        float c0 = 1.0f, c1 = xa;
        m[0] += w;
        m[1] = fmaf(w, c1, m[1]);
        #pragma unroll
        for (int k = 2; k < KM; ++k) {
            float c2 = fmaf(tx, c1, -c0);
            m[k] = fmaf(w, c2, m[k]);
            c0 = c1; c1 = c2;
        }
    }
    float4* out4 = (float4*)(Mrow + (size_t)n * KM);
    out4[0] = make_float4(m[0], m[1], m[2], m[3]);
    out4[1] = make_float4(m[4], m[5], m[6], m[7]);
    out4[2] = make_float4(m[8], m[9], m[10], m[11]);
    out4[3] = make_float4(m[12], m[13], m[14], m[15]);
}

// Fused h2 = silu(M @ D + b2) + graph mean-pool numerator (2-node ILP unroll).
#define P6_NODES 32
__global__ __launch_bounds__(256) void k_h2_pool6(
    const float* __restrict__ Mrow, const float* __restrict__ Dmat,
    const float* __restrict__ b2, const int* __restrict__ batch,
    int N, double* __restrict__ pooled) {
    __shared__ float sM[P6_NODES][KM];   // 2 KB
    __shared__ int sbatch[P6_NODES];
    int tid = threadIdx.x;
    int base = blockIdx.x * P6_NODES;
    if (tid < P6_NODES * 4) {
        int node = tid >> 2, q = tid & 3;
        float4 v = make_float4(0.f, 0.f, 0.f, 0.f);
        if (base + node < N)
            v = ((const float4*)(Mrow + (size_t)(base + node) * KM))[q];
        ((float4*)&sM[node][0])[q] = v;
    }
    if (tid < P6_NODES) {
        int n = base + tid;
        sbatch[tid] = (n < N) ? batch[n] : -1;
    }
    int m = tid;
    bool act = (m < F2);
    float4 d4[KM / 4];
    float bb = 0.0f;
    if (act) {
        #pragma unroll
        for (int k = 0; k < KM / 4; ++k) {
            d4[k].x = Dmat[(4 * k + 0) * F2 + m];
            d4[k].y = Dmat[(4 * k + 1) * F2 + m];
            d4[k].z = Dmat[(4 * k + 2) * F2 + m];
            d4[k].w = Dmat[(4 * k + 3) * F2 + m];
        }
        bb = b2[m];
    }
    __syncthreads();
    double pl = 0.0;
    int gcur = -1;
    int nlim = min(P6_NODES, N - base);
    int i = 0;
    for (; i + 1 < nlim; i += 2) {
        float preA, preB;
        {
            const float4* mA = (const float4*)&sM[i][0];
            const float4* mB = (const float4*)&sM[i + 1][0];
            float4 a0 = mA[0], a1 = mA[1], a2 = mA[2], a3 = mA[3];
            float4 c0 = mB[0], c1 = mB[1], c2 = mB[2], c3 = mB[3];
            float p0 = bb, p1 = 0.f, p2 = 0.f, p3 = 0.f;
            float q0 = bb, q1 = 0.f, q2 = 0.f, q3 = 0.f;
            p0 = fmaf(a0.x, d4[0].x, p0); q0 = fmaf(c0.x, d4[0].x, q0);
            p1 = fmaf(a0.y, d4[0].y, p1); q1 = fmaf(c0.y, d4[0].y, q1);
            p2 = fmaf(a0.z, d4[0].z, p2); q2 = fmaf(c0.z, d4[0].z, q2);
            p3 = fmaf(a0.w, d4[0].w, p3); q3 = fmaf(c0.w, d4[0].w, q3);
            p0 = fmaf(a1.x, d4[1].x, p0); q0 = fmaf(c1.x, d4[1].x, q0);
            p1 = fmaf(a1.y, d4[1].y, p1); q1 = fmaf(c1.y, d4[1].y, q1);
            p2 = fmaf(a1.z, d4[1].z, p2); q2 = fmaf(c1.z, d4[1].z, q2);
            p3 = fmaf(a1.w, d4[1].w, p3); q3 = fmaf(c1.w, d4[1].w, q3);
            p0 = fmaf(a2.x, d4[2].x, p0); q0 = fmaf(c2.x, d4[2].x, q0);
            p1 = fmaf(a2.y, d4[2].y, p1); q1 = fmaf(c2.y, d4[2].y, q1);
            p2 = fmaf(a2.z, d4[2].z, p2); q2 = fmaf(c2.z, d4[2].z, q2);
            p3 = fmaf(a2.w, d4[2].w, p3); q3 = fmaf(c2.w, d4[2].w, q3);
            p0 = fmaf(a3.x, d4[3].x, p0); q0 = fmaf(c3.x, d4[3].x, q0);
            p1 = fmaf(a3.y, d4[3].y, p1); q1 = fmaf(c3.y, d4[3].y, q1);
            p2 = fmaf(a3.z, d4[3].z, p2); q2 = fmaf(c3.z, d4[3].z, q2);
            p3 = fmaf(a3.w, d4[3].w, p3); q3 = fmaf(c3.w, d4[3].w, q3);
            preA = (p0 + p1) + (p2 + p3);
            preB = (q0 + q1) + (q2 + q3);
        }
        float hA = silu_fast(preA);
        float hB = silu_fast(preB);
        int g = sbatch[i];
        if (g != gcur) {
            if (gcur >= 0 && act) atomicAdd(&pooled[(size_t)gcur * F2 + m], pl);
            pl = 0.0;
            gcur = g;
        }
        if (act) pl += (double)hA;
        g = sbatch[i + 1];
        if (g != gcur) {
            if (gcur >= 0 && act) atomicAdd(&pooled[(size_t)gcur * F2 + m], pl);
            pl = 0.0;
            gcur = g;
        }
        if (act) pl += (double)hB;
    }
    if (i < nlim) {
        const float4* m4 = (const float4*)&sM[i][0];
        float4 a0 = m4[0], a1 = m4[1], a2 = m4[2], a3 = m4[3];
        float p0 = bb, p1 = 0.f, p2 = 0.f, p3 = 0.f;
        p0 = fmaf(a0.x, d4[0].x, p0); p1 = fmaf(a0.y, d4[0].y, p1);
        p2 = fmaf(a0.z, d4[0].z, p2); p3 = fmaf(a0.w, d4[0].w, p3);
        p0 = fmaf(a1.x, d4[1].x, p0); p1 = fmaf(a1.y, d4[1].y, p1);
        p2 = fmaf(a1.z, d4[1].z, p2); p3 = fmaf(a1.w, d4[1].w, p3);
        p0 = fmaf(a2.x, d4[2].x, p0); p1 = fmaf(a2.y, d4[2].y, p1);
        p2 = fmaf(a2.z, d4[2].z, p2); p3 = fmaf(a2.w, d4[2].w, p3);
        p0 = fmaf(a3.x, d4[3].x, p0); p1 = fmaf(a3.y, d4[3].y, p1);
        p2 = fmaf(a3.z, d4[3].z, p2); p3 = fmaf(a3.w, d4[3].w, p3);
        float pre = (p0 + p1) + (p2 + p3);
        int g = sbatch[i];
        if (g != gcur) {
            if (gcur >= 0 && act) atomicAdd(&pooled[(size_t)gcur * F2 + m], pl);
            pl = 0.0;
            gcur = g;
        }
        if (act) pl += (double)silu_fast(pre);
    }
    if (gcur >= 0 && act) atomicAdd(&pooled[(size_t)gcur * F2 + m], pl);
}

// ---- fallback path kernels (ws too small for pairs) ----
#define SCHUNK 2048
__global__ __launch_bounds__(256) void k_scan_partial(const int* __restrict__ deg, int N,
                                                      int* __restrict__ partials) {
    __shared__ int red[256];
    int base = blockIdx.x * SCHUNK;
    int s = 0;
    for (int i = threadIdx.x; i < SCHUNK; i += 256) {
        int idx = base + i;
        if (idx < N) s += deg[idx];
    }
    red[threadIdx.x] = s;
    __syncthreads();
    for (int ofs = 128; ofs > 0; ofs >>= 1) {
        if (threadIdx.x < ofs) red[threadIdx.x] += red[threadIdx.x + ofs];
        __syncthreads();
    }
    if (threadIdx.x == 0) partials[blockIdx.x] = red[0];
}
__global__ __launch_bounds__(1024) void k_scan_blocks(int* __restrict__ partials, int nb) {
    __shared__ int sh[1024];
    int t = threadIdx.x;
    int v = (t < nb) ? partials[t] : 0;
    sh[t] = v;
    __syncthreads();
    for (int ofs = 1; ofs < 1024; ofs <<= 1) {
        int u = (t >= ofs) ? sh[t - ofs] : 0;
        __syncthreads();
        sh[t] += u;
        __syncthreads();
    }
    if (t < nb) partials[t] = sh[t] - v;
}
__global__ __launch_bounds__(256) void k_scan_final(const int* __restrict__ deg, int N,
                                                    const int* __restrict__ partials,
                                                    int* __restrict__ off) {
    __shared__ int sh[256];
    int base = blockIdx.x * SCHUNK;
    int i0 = base + threadIdx.x * 8;
    int v[8];
    int s = 0;
    #pragma unroll
    for (int j = 0; j < 8; ++j) {
        int idx = i0 + j;
        v[j] = (idx < N) ? deg[idx] : 0;
        s += v[j];
    }
    int mine = s;
    sh[threadIdx.x] = s;
    __syncthreads();
    for (int ofs = 1; ofs < 256; ofs <<= 1) {
        int u = (threadIdx.x >= ofs) ? sh[threadIdx.x - ofs] : 0;
        __syncthreads();
        sh[threadIdx.x] += u;
        __syncthreads();
    }
    int run = partials[blockIdx.x] + sh[threadIdx.x] - mine;
    #pragma unroll
    for (int j = 0; j < 8; ++j) {
        int idx = i0 + j;
        if (idx < N) { off[idx] = run; run += v[j]; }
    }
    if (N >= i0 && N <= i0 + 8) off[N] = run;
}
__global__ void k_count_deg(const int* __restrict__ dst, int E, int* __restrict__ deg) {
    int i = blockIdx.x * blockDim.x + threadIdx.x;
    if (i < E) atomicAdd(&deg[dst[i]], 1);
}
__global__ void k_dinv_self(const int* __restrict__ deg, const float* __restrict__ x, int N,
                            float* __restrict__ dinv, float* __restrict__ aggx) {
    int i = blockIdx.x * blockDim.x + threadIdx.x;
    if (i < N) {
        float d = 1.0f / sqrtf((float)deg[i] + 1.0f);
        dinv[i] = d;
        aggx[i] = x[i] * d * d;
    }
}
__global__ void k_fill_agg(const int* __restrict__ src, const int* __restrict__ dst, int E,
                           const int* __restrict__ off, int* __restrict__ cursor,
                           int* __restrict__ nbr,
                           const float* __restrict__ x, const float* __restrict__ dinv,
                           float* __restrict__ aggx) {
    int e = blockIdx.x * blockDim.x + threadIdx.x;
    if (e < E) {
        int s = src[e], d = dst[e];
        int p = atomicAdd(&cursor[d], 1);
        nbr[off[d] + p] = s;
        atomicAdd(&aggx[d], x[s] * dinv[s] * dinv[d]);
    }
}
__global__ __launch_bounds__(256) void k_aggh(
    const int* __restrict__ off, const int* __restrict__ nbr,
    const float* __restrict__ aggx, const float* __restrict__ dinv,
    const float* __restrict__ W1, const float* __restrict__ b1,
    int N, float* __restrict__ aggh) {
    int wave = threadIdx.x >> 6;
    int lane = threadIdx.x & 63;
    int n = blockIdx.x * 4 + wave;
    if (n >= N) return;
    int ja = lane, jb = lane + 64;
    float w1a = (ja < F1) ? W1[ja] : 0.0f;
    float b1a = (ja < F1) ? b1[ja] : 0.0f;
    float w1b = (jb < F1) ? W1[jb] : 0.0f;
    float b1b = (jb < F1) ? b1[jb] : 0.0f;
    float d0 = dinv[n];
    float a0 = aggx[n];
    float accA = silu_fast(fmaf(a0, w1a, b1a)) * (d0 * d0);
    float accB = silu_fast(fmaf(a0, w1b, b1b)) * (d0 * d0);
    int beg = off[n], end = off[n + 1];
    for (int t = beg; t < end; t += 64) {
        int cnt = min(64, end - t);
        float sa = 0.0f, sw = 0.0f;
        if (lane < cnt) {
            int s = nbr[t + lane];
            sa = aggx[s];
            sw = dinv[s] * d0;
        }
        for (int i = 0; i < cnt; ++i) {
            float ai = __shfl(sa, i);
            float wi = __shfl(sw, i);
            accA = fmaf(wi, silu_fast(fmaf(ai, w1a, b1a)), accA);
            accB = fmaf(wi, silu_fast(fmaf(ai, w1b, b1b)), accB);
        }
    }
    if (ja < F1) aggh[(size_t)n * F1 + ja] = accA;
    if (jb < F1) aggh[(size_t)n * F1 + jb] = accB;
}
#define HP_NODES 20
#define HP_KT 25
__global__ __launch_bounds__(256) void k_h2_pool3(
    const float* __restrict__ aggh, const float* __restrict__ W2, const float* __restrict__ b2,
    const int* __restrict__ batch, int N, double* __restrict__ pooled) {
    __shared__ float smem[HP_KT * F2 + HP_NODES * (F1 + 1)];
    float* sW = smem;
    float* sA = smem + HP_KT * F2;
    float* sOut = smem;
    __shared__ int sbatch[HP_NODES];
    int tid = threadIdx.x;
    int base = blockIdx.x * HP_NODES;
    for (int idx = tid; idx < HP_NODES * (F1 / 4); idx += 256) {
        int i = idx / (F1 / 4), q = idx % (F1 / 4);
        int n = base + i;
        float4 v = make_float4(0.f, 0.f, 0.f, 0.f);
        if (n < N) v = *(const float4*)(aggh + (size_t)n * F1 + q * 4);
        float* dp = &sA[i * (F1 + 1) + q * 4];
        dp[0] = v.x; dp[1] = v.y; dp[2] = v.z; dp[3] = v.w;
    }
    if (tid < HP_NODES) {
        int n = base + tid;
        sbatch[tid] = (n < N) ? batch[n] : -1;
    }
    const int fgrp = tid % 50;
    const int ngrp = tid / 50;
    const int m0 = fgrp * 4;
    const int i0 = ngrp * 4;
    const bool act = (tid < 250);
    float acc[4][4];
    #pragma unroll
    for (int i = 0; i < 4; ++i)
        #pragma unroll
        for (int j = 0; j < 4; ++j) acc[i][j] = 0.0f;
    for (int kt = 0; kt < F1; kt += HP_KT) {
        __syncthreads();
        for (int idx = tid; idx < (HP_KT * F2) / 4; idx += 256)
            ((float4*)sW)[idx] = ((const float4*)(W2 + (size_t)kt * F2))[idx];
        __syncthreads();
        if (act) {
            #pragma unroll
            for (int kk = 0; kk < HP_KT; ++kk) {
                float4 w = *(const float4*)&sW[kk * F2 + m0];
                int k = kt + kk;
                float a0 = sA[(i0 + 0) * (F1 + 1) + k];
                float a1 = sA[(i0 + 1) * (F1 + 1) + k];
                float a2 = sA[(i0 + 2) * (F1 + 1) + k];
                float a3 = sA[(i0 + 3) * (F1 + 1) + k];
                acc[0][0] = fmaf(a0, w.x, acc[0][0]); acc[0][1] = fmaf(a0, w.y, acc[0][1]);
                acc[0][2] = fmaf(a0, w.z, acc[0][2]); acc[0][3] = fmaf(a0, w.w, acc[0][3]);
                acc[1][0] = fmaf(a1, w.x, acc[1][0]); acc[1][1] = fmaf(a1, w.y, acc[1][1]);
                acc[1][2] = fmaf(a1, w.z, acc[1][2]); acc[1][3] = fmaf(a1, w.w, acc[1][3]);
                acc[2][0] = fmaf(a2, w.x, acc[2][0]); acc[2][1] = fmaf(a2, w.y, acc[2][1]);
                acc[2][2] = fmaf(a2, w.z, acc[2][2]); acc[2][3] = fmaf(a2, w.w, acc[2][3]);
                acc[3][0] = fmaf(a3, w.x, acc[3][0]); acc[3][1] = fmaf(a3, w.y, acc[3][1]);
                acc[3][2] = fmaf(a3, w.z, acc[3][2]); acc[3][3] = fmaf(a3, w.w, acc[3][3]);
            }
        }
    }
    __syncthreads();
    if (act) {
        float4 bb = *(const float4*)(b2 + m0);
        #pragma unroll
        for (int i = 0; i < 4; ++i) {
            float4 r;
            r.x = siluf(acc[i][0] + bb.x);
            r.y = siluf(acc[i][1] + bb.y);
            r.z = siluf(acc[i][2] + bb.z);
            r.w = siluf(acc[i][3] + bb.w);
            *(float4*)&sOut[(i0 + i) * F2 + m0] = r;
        }
    }
    __syncthreads();
    if (tid < F2) {
        double pl = 0.0;
        int gcur = -1;
        for (int i = 0; i < HP_NODES; ++i) {
            int n = base + i;
            if (n >= N) break;
            int g = sbatch[i];
            if (g != gcur) {
                if (gcur >= 0) atomicAdd(&pooled[(size_t)gcur * F2 + tid], pl);
                pl = 0.0;
                gcur = g;
            }
            pl += (double)sOut[i * F2 + tid];
        }
        if (gcur >= 0) atomicAdd(&pooled[(size_t)gcur * F2 + tid], pl);
    }
}

// Head MLP: one block per graph, double precision.
__global__ __launch_bounds__(256) void k_head(
    const double* __restrict__ pooled, const int* __restrict__ counts,
    const float* __restrict__ Wl1, const float* __restrict__ bl1,
    const float* __restrict__ Wl2, const float* __restrict__ bl2,
    float* __restrict__ out) {
    int g = blockIdx.x;
    int tid = threadIdx.x;
    __shared__ double sp[F2];
    __shared__ double red[256];
    double icnt = 1.0 / (double)max(counts[g], 1);
    for (int m = tid; m < F2; m += 256) sp[m] = pooled[(size_t)g * F2 + m] * icnt;
    __syncthreads();
    double part = 0.0;
    if (tid < 100) {
        double acc = (double)bl1[tid];
        #pragma unroll 4
        for (int m = 0; m < F2; ++m) acc += sp[m] * (double)Wl1[m * 100 + tid];
        double t1 = acc / (1.0 + exp(-acc));
        part = t1 * (double)Wl2[tid];
    }
    red[tid] = part;
    __syncthreads();
    for (int s = 128; s > 0; s >>= 1) {
        if (tid < s) red[tid] += red[tid + s];
        __syncthreads();
    }
    if (tid == 0) out[g] = (float)(red[0] + (double)bl2[0]);
}

extern "C" void kernel_launch(void* const* d_in, const int* in_sizes, int n_in,
                              void* d_out, int out_size, void* d_ws, size_t ws_size,
                              hipStream_t stream)
{
    const float* x   = (const float*)d_in[0];
    const int*   src = (const int*)d_in[1];
    const int*   dst = (const int*)d_in[2];
    const int*   batch = (const int*)d_in[3];
    const float* W1  = (const float*)d_in[4];
    const float* b1  = (const float*)d_in[5];
    const float* W2  = (const float*)d_in[6];
    const float* b2  = (const float*)d_in[7];
    const float* Wl1 = (const float*)d_in[8];
    const float* bl1 = (const float*)d_in[9];
    const float* Wl2 = (const float*)d_in[10];
    const float* bl2 = (const float*)d_in[11];
    int N = in_sizes[0];
    int E = in_sizes[1];
    int G = out_size;
    float* out = (float*)d_out;

    char* ws = (char*)d_ws;
    size_t o = 0;
    auto alloc = [&](size_t bytes) -> void* {
        o = (o + 255) & ~(size_t)255;
        void* p = ws + o;
        o += bytes;
        return p;
    };
    int nscan = (N + SCHUNK - 1) / SCHUNK;
    int nbk = (N + BW - 1) / BW;
    int*    deg    = (int*)alloc((size_t)N * 4);
    int*    cursor = (int*)alloc((size_t)N * 4);
    int*    off    = (int*)alloc((size_t)(N + 1) * 4);
    int*    nbr    = (int*)alloc((size_t)E * 4);
    float*  dinv   = (float*)alloc((size_t)N * 4);
    float*  aggx   = (float*)alloc((size_t)N * 4);   // fallback only
    float*  yv     = (float*)alloc((size_t)N * 4);   // y = x*dinv (bucket path)
    float*  aggh   = (float*)alloc((size_t)N * F1 * 4);  // fallback only
    double* pooled = (double*)alloc((size_t)G * F2 * 8);
    int*    counts = (int*)alloc((size_t)G * 4);
    int*    starts = (int*)alloc((size_t)(G + 1) * 4);
    int*    partials = (int*)alloc((size_t)nscan * 4);
    int*    bcnt   = (int*)alloc((size_t)nbk * 4);
    int*    bbase  = (int*)alloc((size_t)(nbk + 1) * 4);
    int*    bcur   = (int*)alloc((size_t)nbk * 4);
    float2* aggxd  = (float2*)alloc((size_t)N * 8);
    float*  Mrow   = (float*)alloc((size_t)N * KM * 4);
    float*  Dmat   = (float*)alloc((size_t)KM * F2 * 4);
    double* clbuf  = (double*)alloc((size_t)KM * F1 * 8);
    float*  scal   = (float*)alloc(2 * 4);
    unsigned* amaxb = (unsigned*)alloc(4);
    // gated large buffer: bucketed edge pairs (last)
    o = (o + 255) & ~(size_t)255;
    unsigned long long* pairs = (unsigned long long*)(ws + o);
    bool use_bucket = (o + (size_t)E * 8) <= ws_size;

    int tE = (E + 255) / 256;
    int tN = (N + 255) / 256;

    if (use_bucket) {
        // fused prologue: batch bounds + zero pooled/bcnt/amax (replaces 3 memsets + 1 kernel)
        k_prep<<<PREP_BLOCKS, 256, 0, stream>>>(batch, N, G, nbk, starts, counts, pooled, bcnt, amaxb);
        k_bucket_count<<<240, 256, nbk * 4, stream>>>(dst, E, nbk, bcnt);
        k_bucket_scan<<<1, 256, 0, stream>>>(bcnt, nbk, E, bbase, bcur);
        k_bucket_scatter<<<240, 256, 0, stream>>>(src, dst, E, nbk, bcur, pairs);
        k_bucket_degoff<<<nbk, 512, 0, stream>>>(pairs, bbase, x, N, dinv, yv, off);
        k_bucket_fill<<<nbk, 512, 0, stream>>>(pairs, bbase, off, yv, dinv, N, nbr, aggxd, amaxb);
        k_fit_coef<<<F1, 64, 0, stream>>>(W1, b1, amaxb, clbuf, scal);
        k_fit_fold<<<(KM * F2 + 255) / 256, 256, 0, stream>>>(clbuf, W2, Dmat);
        k_moments<<<(N + 255) / 256, 256, 0, stream>>>(off, nbr, aggxd, scal, N, Mrow);
        k_h2_pool6<<<(N + P6_NODES - 1) / P6_NODES, 256, 0, stream>>>(Mrow, Dmat, b2, batch, N, pooled);
    } else {
        k_prep<<<PREP_BLOCKS, 256, 0, stream>>>(batch, N, G, nbk, starts, counts, pooled, bcnt, amaxb);
        hipMemsetAsync(deg, 0, (size_t)N * 4, stream);
        hipMemsetAsync(cursor, 0, (size_t)N * 4, stream);
        k_count_deg<<<tE, 256, 0, stream>>>(dst, E, deg);
        k_dinv_self<<<tN, 256, 0, stream>>>(deg, x, N, dinv, aggx);
        k_scan_partial<<<nscan, 256, 0, stream>>>(deg, N, partials);
        k_scan_blocks<<<1, 1024, 0, stream>>>(partials, nscan);
        k_scan_final<<<nscan, 256, 0, stream>>>(deg, N, partials, off);
        k_fill_agg<<<tE, 256, 0, stream>>>(src, dst, E, off, cursor, nbr, x, dinv, aggx);
        k_aggh<<<(N + 3) / 4, 256, 0, stream>>>(off, nbr, aggx, dinv, W1, b1, N, aggh);
        k_h2_pool3<<<(N + HP_NODES - 1) / HP_NODES, 256, 0, stream>>>(aggh, W2, b2, batch, N, pooled);
    }
    k_head<<<G, 256, 0, stream>>>(pooled, counts, Wl1, bl1, Wl2, bl2, out);
}

// Round 19
// 144.732 us; speedup vs baseline: 2.1887x; 1.0677x over previous
//
#include <hip/hip_runtime.h>
#include <math.h>

#define F1 100
#define F2 200
#define KM 16          // Chebyshev moments
#define BW_LOG 9
#define BW 512

__device__ __forceinline__ float siluf(float v) {
    return v / (1.0f + expf(-v));   // precise
}
__device__ __forceinline__ float silu_fast(float v) {
    return __fdividef(v, 1.0f + __expf(-v));
}

// Fused prologue: batch bounds (block 0) + zero pooled (all blocks) + zero bcnt/amax (block 1).
#define PREP_BLOCKS 16
__global__ __launch_bounds__(256) void k_prep(
    const int* __restrict__ batch, int N, int G, int nbk,
    int* __restrict__ starts, int* __restrict__ counts,
    double* __restrict__ pooled, int* __restrict__ bcnt, unsigned* __restrict__ amax) {
    int t = threadIdx.x;
    int b = blockIdx.x;
    for (int idx = b * 256 + t; idx < G * F2; idx += PREP_BLOCKS * 256)
        pooled[idx] = 0.0;
    if (b == 1) {
        for (int i = t; i < nbk; i += 256) bcnt[i] = 0;
        if (t == 0) *amax = 0u;
    }
    if (b == 0) {
        if (t <= G) {
            int lo = 0, hi = N;
            while (lo < hi) {
                int mid = (lo + hi) >> 1;
                if (batch[mid] < t) lo = mid + 1; else hi = mid;
            }
            starts[t] = lo;
        }
        __syncthreads();
        if (t < G) counts[t] = starts[t + 1] - starts[t];
    }
}

// ---- bucketed CSR build ----
__global__ __launch_bounds__(256) void k_bucket_count(const int* __restrict__ dst, int E,
                                                      int nbk, int* __restrict__ gcnt) {
    extern __shared__ int cnt[];
    for (int i = threadIdx.x; i < nbk; i += 256) cnt[i] = 0;
    __syncthreads();
    for (int e = blockIdx.x * 256 + threadIdx.x; e < E; e += gridDim.x * 256)
        atomicAdd(&cnt[dst[e] >> BW_LOG], 1);
    __syncthreads();
    for (int i = threadIdx.x; i < nbk; i += 256)
        if (cnt[i]) atomicAdd(&gcnt[i], cnt[i]);
}

__global__ __launch_bounds__(256) void k_bucket_scan(const int* __restrict__ gcnt, int nbk, int E,
                                                     int* __restrict__ base, int* __restrict__ cursor) {
    __shared__ int sh[256];
    int t = threadIdx.x;
    int v = (t < nbk) ? gcnt[t] : 0;
    sh[t] = v;
    __syncthreads();
    for (int ofs = 1; ofs < 256; ofs <<= 1) {
        int u = (t >= ofs) ? sh[t - ofs] : 0;
        __syncthreads();
        sh[t] += u;
        __syncthreads();
    }
    if (t < nbk) { int ex = sh[t] - v; base[t] = ex; cursor[t] = ex; }
    if (t == 0) base[nbk] = E;
}

#define CROUND 4096
#define CEPT 16
__global__ __launch_bounds__(256) void k_bucket_scatter(
    const int* __restrict__ src, const int* __restrict__ dst, int E, int nbk,
    int* __restrict__ gcursor, unsigned long long* __restrict__ pairs) {
    __shared__ int cnt[256];
    __shared__ int scanb[256];
    __shared__ int startx[256];
    __shared__ int cur[256];
    __shared__ int gbase[256];
    __shared__ unsigned long long stage[CROUND];
    int tid = threadIdx.x;
    for (long long r0 = (long long)blockIdx.x * CROUND; r0 < E; r0 += (long long)gridDim.x * CROUND) {
        cnt[tid] = 0;
        __syncthreads();
        int ss[CEPT], dd[CEPT], bb[CEPT];
        bool va[CEPT];
        #pragma unroll
        for (int j = 0; j < CEPT; ++j) {
            long long e = r0 + j * 256 + tid;
            va[j] = (e < E);
            if (va[j]) {
                ss[j] = src[e]; dd[j] = dst[e]; bb[j] = dd[j] >> BW_LOG;
                atomicAdd(&cnt[bb[j]], 1);
            }
        }
        __syncthreads();
        scanb[tid] = cnt[tid];
        __syncthreads();
        for (int ofs = 1; ofs < 256; ofs <<= 1) {
            int u = (tid >= ofs) ? scanb[tid - ofs] : 0;
            __syncthreads();
            scanb[tid] += u;
            __syncthreads();
        }
        int ex = scanb[tid] - cnt[tid];
        startx[tid] = ex;
        cur[tid] = ex;
        if (tid < nbk && cnt[tid] > 0) gbase[tid] = atomicAdd(&gcursor[tid], cnt[tid]);
        __syncthreads();
        int total = scanb[255];
        #pragma unroll
        for (int j = 0; j < CEPT; ++j) {
            if (va[j]) {
                int slot = atomicAdd(&cur[bb[j]], 1);
                stage[slot] = ((unsigned long long)(unsigned)dd[j] << 32) | (unsigned)ss[j];
            }
        }
        __syncthreads();
        for (int i = tid; i < total; i += 256) {
            unsigned long long p = stage[i];
            int b = (int)(p >> 32) >> BW_LOG;
            pairs[gbase[b] + (i - startx[b])] = p;
        }
        __syncthreads();
    }
}

// deg histogram + dinv + y=x*dinv + intra-bucket scan -> global CSR off
__global__ __launch_bounds__(512) void k_bucket_degoff(
    const unsigned long long* __restrict__ pairs, const int* __restrict__ bbase,
    const float* __restrict__ x, int N,
    float* __restrict__ dinv, float* __restrict__ y, int* __restrict__ off) {
    __shared__ int dl[BW];
    __shared__ int sc[BW];
    int b = blockIdx.x;
    int t = threadIdx.x;
    dl[t] = 0;
    __syncthreads();
    int beg = bbase[b], end = bbase[b + 1];
    for (int i = beg + t; i < end; i += 512)
        atomicAdd(&dl[(int)(pairs[i] >> 32) & (BW - 1)], 1);
    __syncthreads();
    int node = (b << BW_LOG) + t;
    int dg = dl[t];
    if (node < N) {
        float d = 1.0f / sqrtf((float)dg + 1.0f);
        dinv[node] = d;
        y[node] = x[node] * d;
    }
    sc[t] = dg;
    __syncthreads();
    for (int ofs = 1; ofs < BW; ofs <<= 1) {
        int u = (t >= ofs) ? sc[t - ofs] : 0;
        __syncthreads();
        sc[t] += u;
        __syncthreads();
    }
    if (node < N) off[node] = beg + sc[t] - dg;
    if (node == N - 1) off[N] = beg + sc[t];
}

// CSR fill (LDS cursors) + layer-1 scalar agg (single random read y[s]) -> aggxd; block-max -> amax.
__global__ __launch_bounds__(512) void k_bucket_fill(
    const unsigned long long* __restrict__ pairs, const int* __restrict__ bbase,
    const int* __restrict__ off, const float* __restrict__ y, const float* __restrict__ dinv,
    int N, int* __restrict__ nbr, float2* __restrict__ aggxd, unsigned* __restrict__ amax) {
    __shared__ int offl[BW];
    __shared__ int cur[BW];
    __shared__ float agg[BW];
    int b = blockIdx.x;
    int t = threadIdx.x;
    int node0 = b << BW_LOG;
    int node = node0 + t;
    offl[t] = (node < N) ? off[node] : 0;
    cur[t] = 0;
    agg[t] = 0.0f;
    __syncthreads();
    int beg = bbase[b], end = bbase[b + 1];
    for (int i = beg + t; i < end; i += 512) {
        unsigned long long p = pairs[i];
        int s = (int)(p & 0xffffffffu);
        int d = (int)(p >> 32);
        int l = d & (BW - 1);
        int pos = atomicAdd(&cur[l], 1);
        nbr[offl[l] + pos] = s;
        atomicAdd(&agg[l], y[s]);
    }
    __syncthreads();
    float av = 0.0f;
    if (node < N) {
        float dn = dinv[node];
        float a = dn * (agg[t] + y[node]);
        aggxd[node] = make_float2(a, dn);
        av = fabsf(a);
    }
    __syncthreads();
    agg[t] = av;
    __syncthreads();
    for (int ofs = 256; ofs > 0; ofs >>= 1) {
        if (t < ofs) agg[t] = fmaxf(agg[t], agg[t + ofs]);
        __syncthreads();
    }
    if (t == 0) atomicMax(amax, __float_as_uint(agg[0]));
}

// Fit stage 1: Chebyshev coefficients cl[k][j] of g(a,j)=silu(a*W1[j]+b1[j]) on [-A,A].
__global__ __launch_bounds__(64) void k_fit_coef(
    const float* __restrict__ W1, const float* __restrict__ b1,
    const unsigned* __restrict__ amax_bits,
    double* __restrict__ cl /* [KM][F1] */, float* __restrict__ scal /* {A, invA} */) {
    int j = blockIdx.x;
    int i = threadIdx.x;
    float A = __uint_as_float(*amax_bits);
    if (!(A > 0.0f)) A = 1.0f;
    A *= 1.000001f;
    if (j == 0 && i == 0) { scal[0] = A; scal[1] = 1.0f / A; }
    const double PI = 3.14159265358979323846;
    double th = (i + 0.5) * (PI / 64.0);
    double xx = cos(th);
    double w = (double)W1[j] * (double)A;
    double u = w * xx + (double)b1[j];
    double f = u / (1.0 + exp(-u));
    double acc[KM];
    {
        double c0 = 1.0, c1 = xx;
        acc[0] = f;
        acc[1] = f * xx;
        #pragma unroll
        for (int k = 2; k < KM; ++k) {
            double c2 = 2.0 * xx * c1 - c0;
            acc[k] = f * c2;
            c0 = c1; c1 = c2;
        }
    }
    #pragma unroll
    for (int k = 0; k < KM; ++k) {
        double v = acc[k];
        for (int ofs = 32; ofs > 0; ofs >>= 1)
            v += __shfl_down(v, ofs);
        if (i == 0) cl[k * F1 + j] = v * ((k == 0 ? 1.0 : 2.0) / 64.0);
    }
}

// Fit stage 2: fold through W2: D[k][m] = sum_j cl[k][j] * W2[j][m].
__global__ __launch_bounds__(256) void k_fit_fold(
    const double* __restrict__ cl, const float* __restrict__ W2,
    float* __restrict__ Dmat /* [KM][F2] */) {
    __shared__ double scl[KM * F1];
    int tid = threadIdx.x;
    for (int idx = tid; idx < KM * F1; idx += 256) scl[idx] = cl[idx];
    __syncthreads();
    int idx = blockIdx.x * 256 + tid;
    if (idx >= KM * F2) return;
    int k = idx / F2, m = idx % F2;
    double s = 0.0;
    #pragma unroll 4
    for (int j = 0; j < F1; ++j)
        s += scl[k * F1 + j] * (double)W2[j * F2 + m];
    Dmat[idx] = (float)s;
}

// Fused moments + h2 + graph mean-pool: one block per 32 nodes.
// Phase 1: 8 threads/node accumulate U_k = sum dinv_s*T_k(a_s/A) over neighbor
// slices, 3-step shfl tree (width 8), lane 0 adds self term -> sM.
// Phase 2: thread-per-feature h2 = silu(M@D + b2), segmented double pooling.
#define P7_NODES 32
__global__ __launch_bounds__(256) void k_h2_pool7(
    const int* __restrict__ off, const int* __restrict__ nbr,
    const float2* __restrict__ aggxd, const float* __restrict__ scal,
    const float* __restrict__ Dmat, const float* __restrict__ b2,
    const int* __restrict__ batch, int N, double* __restrict__ pooled) {
    __shared__ float sM[P7_NODES][KM];   // 2 KB
    __shared__ int sbatch[P7_NODES];
    int tid = threadIdx.x;
    int base = blockIdx.x * P7_NODES;
    if (tid < P7_NODES) {
        int n = base + tid;
        sbatch[tid] = (n < N) ? batch[n] : -1;
    }
    int m = tid;
    bool act = (m < F2);
    float4 d4[KM / 4];
    float bb = 0.0f;
    if (act) {
        #pragma unroll
        for (int k = 0; k < KM / 4; ++k) {
            d4[k].x = Dmat[(4 * k + 0) * F2 + m];
            d4[k].y = Dmat[(4 * k + 1) * F2 + m];
            d4[k].z = Dmat[(4 * k + 2) * F2 + m];
            d4[k].w = Dmat[(4 * k + 3) * F2 + m];
        }
        bb = b2[m];
    }
    // ---- phase 1: moments for this block's 32 nodes ----
    {
        int g = tid >> 3;            // node group 0..31
        int l = tid & 7;             // lane within group
        int node = base + g;
        float invA = scal[1];
        float u[KM];
        #pragma unroll
        for (int k = 0; k < KM; ++k) u[k] = 0.0f;
        if (node < N) {
            int beg = off[node], end = off[node + 1];
            for (int e = beg + l; e < end; e += 8) {
                int s = nbr[e];
                float2 q = aggxd[s];
                float w = q.y;                 // dinv_s
                float xa = q.x * invA;
                float tx = xa + xa;
                float c0 = 1.0f, c1 = xa;
                u[0] += w;
                u[1] = fmaf(w, c1, u[1]);
                #pragma unroll
                for (int k = 2; k < KM; ++k) {
                    float c2 = fmaf(tx, c1, -c0);
                    u[k] = fmaf(w, c2, u[k]);
                    c0 = c1; c1 = c2;
                }
            }
        }
        #pragma unroll
        for (int k = 0; k < KM; ++k) {
            u[k] += __shfl_down(u[k], 4, 8);
            u[k] += __shfl_down(u[k], 2, 8);
            u[k] += __shfl_down(u[k], 1, 8);
        }
        if (l == 0 && node < N) {
            float2 sd = aggxd[node];
            float d0 = sd.y;
            float d00 = d0 * d0;
            float xa = sd.x * invA;
            float tx = xa + xa;
            float c0 = 1.0f, c1 = xa;
            sM[g][0] = fmaf(d0, u[0], d00);          // T0 = 1
            sM[g][1] = fmaf(d0, u[1], d00 * xa);     // T1 = xa
            #pragma unroll
            for (int k = 2; k < KM; ++k) {
                float c2 = fmaf(tx, c1, -c0);
                sM[g][k] = fmaf(d0, u[k], d00 * c2);
                c0 = c1; c1 = c2;
            }
        }
    }
    __syncthreads();
    // ---- phase 2: h2 + pooling (2-node ILP unroll) ----
    double pl = 0.0;
    int gcur = -1;
    int nlim = min(P7_NODES, N - base);
    int i = 0;
    for (; i + 1 < nlim; i += 2) {
        float preA, preB;
        {
            const float4* mA = (const float4*)&sM[i][0];
            const float4* mB = (const float4*)&sM[i + 1][0];
            float4 a0 = mA[0], a1 = mA[1], a2 = mA[2], a3 = mA[3];
            float4 c0 = mB[0], c1 = mB[1], c2 = mB[2], c3 = mB[3];
            float p0 = bb, p1 = 0.f, p2 = 0.f, p3 = 0.f;
            float q0 = bb, q1 = 0.f, q2 = 0.f, q3 = 0.f;
            p0 = fmaf(a0.x, d4[0].x, p0); q0 = fmaf(c0.x, d4[0].x, q0);
            p1 = fmaf(a0.y, d4[0].y, p1); q1 = fmaf(c0.y, d4[0].y, q1);
            p2 = fmaf(a0.z, d4[0].z, p2); q2 = fmaf(c0.z, d4[0].z, q2);
            p3 = fmaf(a0.w, d4[0].w, p3); q3 = fmaf(c0.w, d4[0].w, q3);
            p0 = fmaf(a1.x, d4[1].x, p0); q0 = fmaf(c1.x, d4[1].x, q0);
            p1 = fmaf(a1.y, d4[1].y, p1); q1 = fmaf(c1.y, d4[1].y, q1);
            p2 = fmaf(a1.z, d4[1].z, p2); q2 = fmaf(c1.z, d4[1].z, q2);
            p3 = fmaf(a1.w, d4[1].w, p3); q3 = fmaf(c1.w, d4[1].w, q3);
            p0 = fmaf(a2.x, d4[2].x, p0); q0 = fmaf(c2.x, d4[2].x, q0);
            p1 = fmaf(a2.y, d4[2].y, p1); q1 = fmaf(c2.y, d4[2].y, q1);
            p2 = fmaf(a2.z, d4[2].z, p2); q2 = fmaf(c2.z, d4[2].z, q2);
            p3 = fmaf(a2.w, d4[2].w, p3); q3 = fmaf(c2.w, d4[2].w, q3);
            p0 = fmaf(a3.x, d4[3].x, p0); q0 = fmaf(c3.x, d4[3].x, q0);
            p1 = fmaf(a3.y, d4[3].y, p1); q1 = fmaf(c3.y, d4[3].y, q1);
            p2 = fmaf(a3.z, d4[3].z, p2); q2 = fmaf(c3.z, d4[3].z, q2);
            p3 = fmaf(a3.w, d4[3].w, p3); q3 = fmaf(c3.w, d4[3].w, q3);
            preA = (p0 + p1) + (p2 + p3);
            preB = (q0 + q1) + (q2 + q3);
        }
        float hA = silu_fast(preA);
        float hB = silu_fast(preB);
        int g = sbatch[i];
        if (g != gcur) {
            if (gcur >= 0 && act) atomicAdd(&pooled[(size_t)gcur * F2 + m], pl);
            pl = 0.0;
            gcur = g;
        }
        if (act) pl += (double)hA;
        g = sbatch[i + 1];
        if (g != gcur) {
            if (gcur >= 0 && act) atomicAdd(&pooled[(size_t)gcur * F2 + m], pl);
            pl = 0.0;
            gcur = g;
        }
        if (act) pl += (double)hB;
    }
    if (i < nlim) {
        const float4* m4 = (const float4*)&sM[i][0];
        float4 a0 = m4[0], a1 = m4[1], a2 = m4[2], a3 = m4[3];
        float p0 = bb, p1 = 0.f, p2 = 0.f, p3 = 0.f;
        p0 = fmaf(a0.x, d4[0].x, p0); p1 = fmaf(a0.y, d4[0].y, p1);
        p2 = fmaf(a0.z, d4[0].z, p2); p3 = fmaf(a0.w, d4[0].w, p3);
        p0 = fmaf(a1.x, d4[1].x, p0); p1 = fmaf(a1.y, d4[1].y, p1);
        p2 = fmaf(a1.z, d4[1].z, p2); p3 = fmaf(a1.w, d4[1].w, p3);
        p0 = fmaf(a2.x, d4[2].x, p0); p1 = fmaf(a2.y, d4[2].y, p1);
        p2 = fmaf(a2.z, d4[2].z, p2); p3 = fmaf(a2.w, d4[2].w, p3);
        p0 = fmaf(a3.x, d4[3].x, p0); p1 = fmaf(a3.y, d4[3].y, p1);
        p2 = fmaf(a3.z, d4[3].z, p2); p3 = fmaf(a3.w, d4[3].w, p3);
        float pre = (p0 + p1) + (p2 + p3);
        int g = sbatch[i];
        if (g != gcur) {
            if (gcur >= 0 && act) atomicAdd(&pooled[(size_t)gcur * F2 + m], pl);
            pl = 0.0;
            gcur = g;
        }
        if (act) pl += (double)silu_fast(pre);
    }
    if (gcur >= 0 && act) atomicAdd(&pooled[(size_t)gcur * F2 + m], pl);
}

// ---- fallback path kernels (ws too small for pairs) ----
#define SCHUNK 2048
__global__ __launch_bounds__(256) void k_scan_partial(const int* __restrict__ deg, int N,
                                                      int* __restrict__ partials) {
    __shared__ int red[256];
    int base = blockIdx.x * SCHUNK;
    int s = 0;
    for (int i = threadIdx.x; i < SCHUNK; i += 256) {
        int idx = base + i;
        if (idx < N) s += deg[idx];
    }
    red[threadIdx.x] = s;
    __syncthreads();
    for (int ofs = 128; ofs > 0; ofs >>= 1) {
        if (threadIdx.x < ofs) red[threadIdx.x] += red[threadIdx.x + ofs];
        __syncthreads();
    }
    if (threadIdx.x == 0) partials[blockIdx.x] = red[0];
}
__global__ __launch_bounds__(1024) void k_scan_blocks(int* __restrict__ partials, int nb) {
    __shared__ int sh[1024];
    int t = threadIdx.x;
    int v = (t < nb) ? partials[t] : 0;
    sh[t] = v;
    __syncthreads();
    for (int ofs = 1; ofs < 1024; ofs <<= 1) {
        int u = (t >= ofs) ? sh[t - ofs] : 0;
        __syncthreads();
        sh[t] += u;
        __syncthreads();
    }
    if (t < nb) partials[t] = sh[t] - v;
}
__global__ __launch_bounds__(256) void k_scan_final(const int* __restrict__ deg, int N,
                                                    const int* __restrict__ partials,
                                                    int* __restrict__ off) {
    __shared__ int sh[256];
    int base = blockIdx.x * SCHUNK;
    int i0 = base + threadIdx.x * 8;
    int v[8];
    int s = 0;
    #pragma unroll
    for (int j = 0; j < 8; ++j) {
        int idx = i0 + j;
        v[j] = (idx < N) ? deg[idx] : 0;
        s += v[j];
    }
    int mine = s;
    sh[threadIdx.x] = s;
    __syncthreads();
    for (int ofs = 1; ofs < 256; ofs <<= 1) {
        int u = (threadIdx.x >= ofs) ? sh[threadIdx.x - ofs] : 0;
        __syncthreads();
        sh[threadIdx.x] += u;
        __syncthreads();
    }
    int run = partials[blockIdx.x] + sh[threadIdx.x] - mine;
    #pragma unroll
    for (int j = 0; j < 8; ++j) {
        int idx = i0 + j;
        if (idx < N) { off[idx] = run; run += v[j]; }
    }
    if (N >= i0 && N <= i0 + 8) off[N] = run;
}
__global__ void k_count_deg(const int* __restrict__ dst, int E, int* __restrict__ deg) {
    int i = blockIdx.x * blockDim.x + threadIdx.x;
    if (i < E) atomicAdd(&deg[dst[i]], 1);
}
__global__ void k_dinv_self(const int* __restrict__ deg, const float* __restrict__ x, int N,
                            float* __restrict__ dinv, float* __restrict__ aggx) {
    int i = blockIdx.x * blockDim.x + threadIdx.x;
    if (i < N) {
        float d = 1.0f / sqrtf((float)deg[i] + 1.0f);
        dinv[i] = d;
        aggx[i] = x[i] * d * d;
    }
}
__global__ void k_fill_agg(const int* __restrict__ src, const int* __restrict__ dst, int E,
                           const int* __restrict__ off, int* __restrict__ cursor,
                           int* __restrict__ nbr,
                           const float* __restrict__ x, const float* __restrict__ dinv,
                           float* __restrict__ aggx) {
    int e = blockIdx.x * blockDim.x + threadIdx.x;
    if (e < E) {
        int s = src[e], d = dst[e];
        int p = atomicAdd(&cursor[d], 1);
        nbr[off[d] + p] = s;
        atomicAdd(&aggx[d], x[s] * dinv[s] * dinv[d]);
    }
}
__global__ __launch_bounds__(256) void k_aggh(
    const int* __restrict__ off, const int* __restrict__ nbr,
    const float* __restrict__ aggx, const float* __restrict__ dinv,
    const float* __restrict__ W1, const float* __restrict__ b1,
    int N, float* __restrict__ aggh) {
    int wave = threadIdx.x >> 6;
    int lane = threadIdx.x & 63;
    int n = blockIdx.x * 4 + wave;
    if (n >= N) return;
    int ja = lane, jb = lane + 64;
    float w1a = (ja < F1) ? W1[ja] : 0.0f;
    float b1a = (ja < F1) ? b1[ja] : 0.0f;
    float w1b = (jb < F1) ? W1[jb] : 0.0f;
    float b1b = (jb < F1) ? b1[jb] : 0.0f;
    float d0 = dinv[n];
    float a0 = aggx[n];
    float accA = silu_fast(fmaf(a0, w1a, b1a)) * (d0 * d0);
    float accB = silu_fast(fmaf(a0, w1b, b1b)) * (d0 * d0);
    int beg = off[n], end = off[n + 1];
    for (int t = beg; t < end; t += 64) {
        int cnt = min(64, end - t);
        float sa = 0.0f, sw = 0.0f;
        if (lane < cnt) {
            int s = nbr[t + lane];
            sa = aggx[s];
            sw = dinv[s] * d0;
        }
        for (int i = 0; i < cnt; ++i) {
            float ai = __shfl(sa, i);
            float wi = __shfl(sw, i);
            accA = fmaf(wi, silu_fast(fmaf(ai, w1a, b1a)), accA);
            accB = fmaf(wi, silu_fast(fmaf(ai, w1b, b1b)), accB);
        }
    }
    if (ja < F1) aggh[(size_t)n * F1 + ja] = accA;
    if (jb < F1) aggh[(size_t)n * F1 + jb] = accB;
}
#define HP_NODES 20
#define HP_KT 25
__global__ __launch_bounds__(256) void k_h2_pool3(
    const float* __restrict__ aggh, const float* __restrict__ W2, const float* __restrict__ b2,
    const int* __restrict__ batch, int N, double* __restrict__ pooled) {
    __shared__ float smem[HP_KT * F2 + HP_NODES * (F1 + 1)];
    float* sW = smem;
    float* sA = smem + HP_KT * F2;
    float* sOut = smem;
    __shared__ int sbatch[HP_NODES];
    int tid = threadIdx.x;
    int base = blockIdx.x * HP_NODES;
    for (int idx = tid; idx < HP_NODES * (F1 / 4); idx += 256) {
        int i = idx / (F1 / 4), q = idx % (F1 / 4);
        int n = base + i;
        float4 v = make_float4(0.f, 0.f, 0.f, 0.f);
        if (n < N) v = *(const float4*)(aggh + (size_t)n * F1 + q * 4);
        float* dp = &sA[i * (F1 + 1) + q * 4];
        dp[0] = v.x; dp[1] = v.y; dp[2] = v.z; dp[3] = v.w;
    }
    if (tid < HP_NODES) {
        int n = base + tid;
        sbatch[tid] = (n < N) ? batch[n] : -1;
    }
    const int fgrp = tid % 50;
    const int ngrp = tid / 50;
    const int m0 = fgrp * 4;
    const int i0 = ngrp * 4;
    const bool act = (tid < 250);
    float acc[4][4];
    #pragma unroll
    for (int i = 0; i < 4; ++i)
        #pragma unroll
        for (int j = 0; j < 4; ++j) acc[i][j] = 0.0f;
    for (int kt = 0; kt < F1; kt += HP_KT) {
        __syncthreads();
        for (int idx = tid; idx < (HP_KT * F2) / 4; idx += 256)
            ((float4*)sW)[idx] = ((const float4*)(W2 + (size_t)kt * F2))[idx];
        __syncthreads();
        if (act) {
            #pragma unroll
            for (int kk = 0; kk < HP_KT; ++kk) {
                float4 w = *(const float4*)&sW[kk * F2 + m0];
                int k = kt + kk;
                float a0 = sA[(i0 + 0) * (F1 + 1) + k];
                float a1 = sA[(i0 + 1) * (F1 + 1) + k];
                float a2 = sA[(i0 + 2) * (F1 + 1) + k];
                float a3 = sA[(i0 + 3) * (F1 + 1) + k];
                acc[0][0] = fmaf(a0, w.x, acc[0][0]); acc[0][1] = fmaf(a0, w.y, acc[0][1]);
                acc[0][2] = fmaf(a0, w.z, acc[0][2]); acc[0][3] = fmaf(a0, w.w, acc[0][3]);
                acc[1][0] = fmaf(a1, w.x, acc[1][0]); acc[1][1] = fmaf(a1, w.y, acc[1][1]);
                acc[1][2] = fmaf(a1, w.z, acc[1][2]); acc[1][3] = fmaf(a1, w.w, acc[1][3]);
                acc[2][0] = fmaf(a2, w.x, acc[2][0]); acc[2][1] = fmaf(a2, w.y, acc[2][1]);
                acc[2][2] = fmaf(a2, w.z, acc[2][2]); acc[2][3] = fmaf(a2, w.w, acc[2][3]);
                acc[3][0] = fmaf(a3, w.x, acc[3][0]); acc[3][1] = fmaf(a3, w.y, acc[3][1]);
                acc[3][2] = fmaf(a3, w.z, acc[3][2]); acc[3][3] = fmaf(a3, w.w, acc[3][3]);
            }
        }
    }
    __syncthreads();
    if (act) {
        float4 bb = *(const float4*)(b2 + m0);
        #pragma unroll
        for (int i = 0; i < 4; ++i) {
            float4 r;
            r.x = siluf(acc[i][0] + bb.x);
            r.y = siluf(acc[i][1] + bb.y);
            r.z = siluf(acc[i][2] + bb.z);
            r.w = siluf(acc[i][3] + bb.w);
            *(float4*)&sOut[(i0 + i) * F2 + m0] = r;
        }
    }
    __syncthreads();
    if (tid < F2) {
        double pl = 0.0;
        int gcur = -1;
        for (int i = 0; i < HP_NODES; ++i) {
            int n = base + i;
            if (n >= N) break;
            int g = sbatch[i];
            if (g != gcur) {
                if (gcur >= 0) atomicAdd(&pooled[(size_t)gcur * F2 + tid], pl);
                pl = 0.0;
                gcur = g;
            }
            pl += (double)sOut[i * F2 + tid];
        }
        if (gcur >= 0) atomicAdd(&pooled[(size_t)gcur * F2 + tid], pl);
    }
}

// Head MLP: one block per graph, double precision.
__global__ __launch_bounds__(256) void k_head(
    const double* __restrict__ pooled, const int* __restrict__ counts,
    const float* __restrict__ Wl1, const float* __restrict__ bl1,
    const float* __restrict__ Wl2, const float* __restrict__ bl2,
    float* __restrict__ out) {
    int g = blockIdx.x;
    int tid = threadIdx.x;
    __shared__ double sp[F2];
    __shared__ double red[256];
    double icnt = 1.0 / (double)max(counts[g], 1);
    for (int m = tid; m < F2; m += 256) sp[m] = pooled[(size_t)g * F2 + m] * icnt;
    __syncthreads();
    double part = 0.0;
    if (tid < 100) {
        double acc = (double)bl1[tid];
        #pragma unroll 4
        for (int m = 0; m < F2; ++m) acc += sp[m] * (double)Wl1[m * 100 + tid];
        double t1 = acc / (1.0 + exp(-acc));
        part = t1 * (double)Wl2[tid];
    }
    red[tid] = part;
    __syncthreads();
    for (int s = 128; s > 0; s >>= 1) {
        if (tid < s) red[tid] += red[tid + s];
        __syncthreads();
    }
    if (tid == 0) out[g] = (float)(red[0] + (double)bl2[0]);
}

extern "C" void kernel_launch(void* const* d_in, const int* in_sizes, int n_in,
                              void* d_out, int out_size, void* d_ws, size_t ws_size,
                              hipStream_t stream)
{
    const float* x   = (const float*)d_in[0];
    const int*   src = (const int*)d_in[1];
    const int*   dst = (const int*)d_in[2];
    const int*   batch = (const int*)d_in[3];
    const float* W1  = (const float*)d_in[4];
    const float* b1  = (const float*)d_in[5];
    const float* W2  = (const float*)d_in[6];
    const float* b2  = (const float*)d_in[7];
    const float* Wl1 = (const float*)d_in[8];
    const float* bl1 = (const float*)d_in[9];
    const float* Wl2 = (const float*)d_in[10];
    const float* bl2 = (const float*)d_in[11];
    int N = in_sizes[0];
    int E = in_sizes[1];
    int G = out_size;
    float* out = (float*)d_out;

    char* ws = (char*)d_ws;
    size_t o = 0;
    auto alloc = [&](size_t bytes) -> void* {
        o = (o + 255) & ~(size_t)255;
        void* p = ws + o;
        o += bytes;
        return p;
    };
    int nscan = (N + SCHUNK - 1) / SCHUNK;
    int nbk = (N + BW - 1) / BW;
    int*    deg    = (int*)alloc((size_t)N * 4);
    int*    cursor = (int*)alloc((size_t)N * 4);
    int*    off    = (int*)alloc((size_t)(N + 1) * 4);
    int*    nbr    = (int*)alloc((size_t)E * 4);
    float*  dinv   = (float*)alloc((size_t)N * 4);
    float*  aggx   = (float*)alloc((size_t)N * 4);   // fallback only
    float*  yv     = (float*)alloc((size_t)N * 4);   // y = x*dinv (bucket path)
    float*  aggh   = (float*)alloc((size_t)N * F1 * 4);  // fallback only
    double* pooled = (double*)alloc((size_t)G * F2 * 8);
    int*    counts = (int*)alloc((size_t)G * 4);
    int*    starts = (int*)alloc((size_t)(G + 1) * 4);
    int*    partials = (int*)alloc((size_t)nscan * 4);
    int*    bcnt   = (int*)alloc((size_t)nbk * 4);
    int*    bbase  = (int*)alloc((size_t)(nbk + 1) * 4);
    int*    bcur   = (int*)alloc((size_t)nbk * 4);
    float2* aggxd  = (float2*)alloc((size_t)N * 8);
    float*  Dmat   = (float*)alloc((size_t)KM * F2 * 4);
    double* clbuf  = (double*)alloc((size_t)KM * F1 * 8);
    float*  scal   = (float*)alloc(2 * 4);
    unsigned* amaxb = (unsigned*)alloc(4);
    // gated large buffer: bucketed edge pairs (last)
    o = (o + 255) & ~(size_t)255;
    unsigned long long* pairs = (unsigned long long*)(ws + o);
    bool use_bucket = (o + (size_t)E * 8) <= ws_size;

    int tE = (E + 255) / 256;
    int tN = (N + 255) / 256;

    if (use_bucket) {
        k_prep<<<PREP_BLOCKS, 256, 0, stream>>>(batch, N, G, nbk, starts, counts, pooled, bcnt, amaxb);
        k_bucket_count<<<240, 256, nbk * 4, stream>>>(dst, E, nbk, bcnt);
        k_bucket_scan<<<1, 256, 0, stream>>>(bcnt, nbk, E, bbase, bcur);
        k_bucket_scatter<<<240, 256, 0, stream>>>(src, dst, E, nbk, bcur, pairs);
        k_bucket_degoff<<<nbk, 512, 0, stream>>>(pairs, bbase, x, N, dinv, yv, off);
        k_bucket_fill<<<nbk, 512, 0, stream>>>(pairs, bbase, off, yv, dinv, N, nbr, aggxd, amaxb);
        k_fit_coef<<<F1, 64, 0, stream>>>(W1, b1, amaxb, clbuf, scal);
        k_fit_fold<<<(KM * F2 + 255) / 256, 256, 0, stream>>>(clbuf, W2, Dmat);
        k_h2_pool7<<<(N + P7_NODES - 1) / P7_NODES, 256, 0, stream>>>(
            off, nbr, aggxd, scal, Dmat, b2, batch, N, pooled);
    } else {
        k_prep<<<PREP_BLOCKS, 256, 0, stream>>>(batch, N, G, nbk, starts, counts, pooled, bcnt, amaxb);
        hipMemsetAsync(deg, 0, (size_t)N * 4, stream);
        hipMemsetAsync(cursor, 0, (size_t)N * 4, stream);
        k_count_deg<<<tE, 256, 0, stream>>>(dst, E, deg);
        k_dinv_self<<<tN, 256, 0, stream>>>(deg, x, N, dinv, aggx);
        k_scan_partial<<<nscan, 256, 0, stream>>>(deg, N, partials);
        k_scan_blocks<<<1, 1024, 0, stream>>>(partials, nscan);
        k_scan_final<<<nscan, 256, 0, stream>>>(deg, N, partials, off);
        k_fill_agg<<<tE, 256, 0, stream>>>(src, dst, E, off, cursor, nbr, x, dinv, aggx);
        k_aggh<<<(N + 3) / 4, 256, 0, stream>>>(off, nbr, aggx, dinv, W1, b1, N, aggh);
        k_h2_pool3<<<(N + HP_NODES - 1) / HP_NODES, 256, 0, stream>>>(aggh, W2, b2, batch, N, pooled);
    }
    k_head<<<G, 256, 0, stream>>>(pooled, counts, Wl1, bl1, Wl2, bl2, out);
}

// Round 20
// 139.692 us; speedup vs baseline: 2.2677x; 1.0361x over previous
//
#include <hip/hip_runtime.h>
#include <math.h>

#define F1 100
#define F2 200
#define KM 12          // Chebyshev moments (rho~17 => trunc ~2e-15 rel, fp32 roundoff dominates)
#define BW_LOG 9
#define BW 512

__device__ __forceinline__ float siluf(float v) {
    return v / (1.0f + expf(-v));   // precise
}
__device__ __forceinline__ float silu_fast(float v) {
    return __fdividef(v, 1.0f + __expf(-v));
}

// Fused prologue: batch bounds (block 0) + zero pooled (all blocks) + zero bcnt/amax (block 1).
#define PREP_BLOCKS 16
__global__ __launch_bounds__(256) void k_prep(
    const int* __restrict__ batch, int N, int G, int nbk,
    int* __restrict__ starts, int* __restrict__ counts,
    double* __restrict__ pooled, int* __restrict__ bcnt, unsigned* __restrict__ amax) {
    int t = threadIdx.x;
    int b = blockIdx.x;
    for (int idx = b * 256 + t; idx < G * F2; idx += PREP_BLOCKS * 256)
        pooled[idx] = 0.0;
    if (b == 1) {
        for (int i = t; i < nbk; i += 256) bcnt[i] = 0;
        if (t == 0) *amax = 0u;
    }
    if (b == 0) {
        if (t <= G) {
            int lo = 0, hi = N;
            while (lo < hi) {
                int mid = (lo + hi) >> 1;
                if (batch[mid] < t) lo = mid + 1; else hi = mid;
            }
            starts[t] = lo;
        }
        __syncthreads();
        if (t < G) counts[t] = starts[t + 1] - starts[t];
    }
}

// ---- bucketed CSR build ----
__global__ __launch_bounds__(256) void k_bucket_count(const int* __restrict__ dst, int E,
                                                      int nbk, int* __restrict__ gcnt) {
    extern __shared__ int cnt[];
    for (int i = threadIdx.x; i < nbk; i += 256) cnt[i] = 0;
    __syncthreads();
    for (int e = blockIdx.x * 256 + threadIdx.x; e < E; e += gridDim.x * 256)
        atomicAdd(&cnt[dst[e] >> BW_LOG], 1);
    __syncthreads();
    for (int i = threadIdx.x; i < nbk; i += 256)
        if (cnt[i]) atomicAdd(&gcnt[i], cnt[i]);
}

__global__ __launch_bounds__(256) void k_bucket_scan(const int* __restrict__ gcnt, int nbk, int E,
                                                     int* __restrict__ base, int* __restrict__ cursor) {
    __shared__ int sh[256];
    int t = threadIdx.x;
    int v = (t < nbk) ? gcnt[t] : 0;
    sh[t] = v;
    __syncthreads();
    for (int ofs = 1; ofs < 256; ofs <<= 1) {
        int u = (t >= ofs) ? sh[t - ofs] : 0;
        __syncthreads();
        sh[t] += u;
        __syncthreads();
    }
    if (t < nbk) { int ex = sh[t] - v; base[t] = ex; cursor[t] = ex; }
    if (t == 0) base[nbk] = E;
}

#define CROUND 4096
#define CEPT 16
__global__ __launch_bounds__(256) void k_bucket_scatter(
    const int* __restrict__ src, const int* __restrict__ dst, int E, int nbk,
    int* __restrict__ gcursor, unsigned long long* __restrict__ pairs) {
    __shared__ int cnt[256];
    __shared__ int scanb[256];
    __shared__ int startx[256];
    __shared__ int cur[256];
    __shared__ int gbase[256];
    __shared__ unsigned long long stage[CROUND];
    int tid = threadIdx.x;
    for (long long r0 = (long long)blockIdx.x * CROUND; r0 < E; r0 += (long long)gridDim.x * CROUND) {
        cnt[tid] = 0;
        __syncthreads();
        int ss[CEPT], dd[CEPT], bb[CEPT];
        bool va[CEPT];
        #pragma unroll
        for (int j = 0; j < CEPT; ++j) {
            long long e = r0 + j * 256 + tid;
            va[j] = (e < E);
            if (va[j]) {
                ss[j] = src[e]; dd[j] = dst[e]; bb[j] = dd[j] >> BW_LOG;
                atomicAdd(&cnt[bb[j]], 1);
            }
        }
        __syncthreads();
        scanb[tid] = cnt[tid];
        __syncthreads();
        for (int ofs = 1; ofs < 256; ofs <<= 1) {
            int u = (tid >= ofs) ? scanb[tid - ofs] : 0;
            __syncthreads();
            scanb[tid] += u;
            __syncthreads();
        }
        int ex = scanb[tid] - cnt[tid];
        startx[tid] = ex;
        cur[tid] = ex;
        if (tid < nbk && cnt[tid] > 0) gbase[tid] = atomicAdd(&gcursor[tid], cnt[tid]);
        __syncthreads();
        int total = scanb[255];
        #pragma unroll
        for (int j = 0; j < CEPT; ++j) {
            if (va[j]) {
                int slot = atomicAdd(&cur[bb[j]], 1);
                stage[slot] = ((unsigned long long)(unsigned)dd[j] << 32) | (unsigned)ss[j];
            }
        }
        __syncthreads();
        for (int i = tid; i < total; i += 256) {
            unsigned long long p = stage[i];
            int b = (int)(p >> 32) >> BW_LOG;
            pairs[gbase[b] + (i - startx[b])] = p;
        }
        __syncthreads();
    }
}

// deg histogram + dinv + y=x*dinv + intra-bucket scan -> global CSR off
__global__ __launch_bounds__(512) void k_bucket_degoff(
    const unsigned long long* __restrict__ pairs, const int* __restrict__ bbase,
    const float* __restrict__ x, int N,
    float* __restrict__ dinv, float* __restrict__ y, int* __restrict__ off) {
    __shared__ int dl[BW];
    __shared__ int sc[BW];
    int b = blockIdx.x;
    int t = threadIdx.x;
    dl[t] = 0;
    __syncthreads();
    int beg = bbase[b], end = bbase[b + 1];
    for (int i = beg + t; i < end; i += 512)
        atomicAdd(&dl[(int)(pairs[i] >> 32) & (BW - 1)], 1);
    __syncthreads();
    int node = (b << BW_LOG) + t;
    int dg = dl[t];
    if (node < N) {
        float d = 1.0f / sqrtf((float)dg + 1.0f);
        dinv[node] = d;
        y[node] = x[node] * d;
    }
    sc[t] = dg;
    __syncthreads();
    for (int ofs = 1; ofs < BW; ofs <<= 1) {
        int u = (t >= ofs) ? sc[t - ofs] : 0;
        __syncthreads();
        sc[t] += u;
        __syncthreads();
    }
    if (node < N) off[node] = beg + sc[t] - dg;
    if (node == N - 1) off[N] = beg + sc[t];
}

// CSR fill (LDS cursors) + layer-1 scalar agg (single random read y[s]) -> aggxd; block-max -> amax.
__global__ __launch_bounds__(512) void k_bucket_fill(
    const unsigned long long* __restrict__ pairs, const int* __restrict__ bbase,
    const int* __restrict__ off, const float* __restrict__ y, const float* __restrict__ dinv,
    int N, int* __restrict__ nbr, float2* __restrict__ aggxd, unsigned* __restrict__ amax) {
    __shared__ int offl[BW];
    __shared__ int cur[BW];
    __shared__ float agg[BW];
    int b = blockIdx.x;
    int t = threadIdx.x;
    int node0 = b << BW_LOG;
    int node = node0 + t;
    offl[t] = (node < N) ? off[node] : 0;
    cur[t] = 0;
    agg[t] = 0.0f;
    __syncthreads();
    int beg = bbase[b], end = bbase[b + 1];
    for (int i = beg + t; i < end; i += 512) {
        unsigned long long p = pairs[i];
        int s = (int)(p & 0xffffffffu);
        int d = (int)(p >> 32);
        int l = d & (BW - 1);
        int pos = atomicAdd(&cur[l], 1);
        nbr[offl[l] + pos] = s;
        atomicAdd(&agg[l], y[s]);
    }
    __syncthreads();
    float av = 0.0f;
    if (node < N) {
        float dn = dinv[node];
        float a = dn * (agg[t] + y[node]);
        aggxd[node] = make_float2(a, dn);
        av = fabsf(a);
    }
    __syncthreads();
    agg[t] = av;
    __syncthreads();
    for (int ofs = 256; ofs > 0; ofs >>= 1) {
        if (t < ofs) agg[t] = fmaxf(agg[t], agg[t + ofs]);
        __syncthreads();
    }
    if (t == 0) atomicMax(amax, __float_as_uint(agg[0]));
}

// Fit stage 1: Chebyshev coefficients cl[k][j] of g(a,j)=silu(a*W1[j]+b1[j]) on [-A,A].
__global__ __launch_bounds__(64) void k_fit_coef(
    const float* __restrict__ W1, const float* __restrict__ b1,
    const unsigned* __restrict__ amax_bits,
    double* __restrict__ cl /* [KM][F1] */, float* __restrict__ scal /* {A, invA} */) {
    int j = blockIdx.x;
    int i = threadIdx.x;
    float A = __uint_as_float(*amax_bits);
    if (!(A > 0.0f)) A = 1.0f;
    A *= 1.000001f;
    if (j == 0 && i == 0) { scal[0] = A; scal[1] = 1.0f / A; }
    const double PI = 3.14159265358979323846;
    double th = (i + 0.5) * (PI / 64.0);
    double xx = cos(th);
    double w = (double)W1[j] * (double)A;
    double u = w * xx + (double)b1[j];
    double f = u / (1.0 + exp(-u));
    double acc[KM];
    {
        double c0 = 1.0, c1 = xx;
        acc[0] = f;
        acc[1] = f * xx;
        #pragma unroll
        for (int k = 2; k < KM; ++k) {
            double c2 = 2.0 * xx * c1 - c0;
            acc[k] = f * c2;
            c0 = c1; c1 = c2;
        }
    }
    #pragma unroll
    for (int k = 0; k < KM; ++k) {
        double v = acc[k];
        for (int ofs = 32; ofs > 0; ofs >>= 1)
            v += __shfl_down(v, ofs);
        if (i == 0) cl[k * F1 + j] = v * ((k == 0 ? 1.0 : 2.0) / 64.0);
    }
}

// Fit stage 2: fold through W2: D[k][m] = sum_j cl[k][j] * W2[j][m].
__global__ __launch_bounds__(256) void k_fit_fold(
    const double* __restrict__ cl, const float* __restrict__ W2,
    float* __restrict__ Dmat /* [KM][F2] */) {
    __shared__ double scl[KM * F1];
    int tid = threadIdx.x;
    for (int idx = tid; idx < KM * F1; idx += 256) scl[idx] = cl[idx];
    __syncthreads();
    int idx = blockIdx.x * 256 + tid;
    if (idx >= KM * F2) return;
    int k = idx / F2, m = idx % F2;
    double s = 0.0;
    #pragma unroll 4
    for (int j = 0; j < F1; ++j)
        s += scl[k * F1 + j] * (double)W2[j * F2 + m];
    Dmat[idx] = (float)s;
}

// Fused moments + h2 + graph mean-pool: one block per 32 nodes.
#define P7_NODES 32
__global__ __launch_bounds__(256) void k_h2_pool7(
    const int* __restrict__ off, const int* __restrict__ nbr,
    const float2* __restrict__ aggxd, const float* __restrict__ scal,
    const float* __restrict__ Dmat, const float* __restrict__ b2,
    const int* __restrict__ batch, int N, double* __restrict__ pooled) {
    __shared__ float sM[P7_NODES][KM];   // 1.5 KB
    __shared__ int sbatch[P7_NODES];
    int tid = threadIdx.x;
    int base = blockIdx.x * P7_NODES;
    if (tid < P7_NODES) {
        int n = base + tid;
        sbatch[tid] = (n < N) ? batch[n] : -1;
    }
    int m = tid;
    bool act = (m < F2);
    float4 d4[KM / 4];
    float bb = 0.0f;
    if (act) {
        #pragma unroll
        for (int k = 0; k < KM / 4; ++k) {
            d4[k].x = Dmat[(4 * k + 0) * F2 + m];
            d4[k].y = Dmat[(4 * k + 1) * F2 + m];
            d4[k].z = Dmat[(4 * k + 2) * F2 + m];
            d4[k].w = Dmat[(4 * k + 3) * F2 + m];
        }
        bb = b2[m];
    }
    // ---- phase 1: moments for this block's 32 nodes (8 threads/node) ----
    {
        int g = tid >> 3;
        int l = tid & 7;
        int node = base + g;
        float invA = scal[1];
        float u[KM];
        #pragma unroll
        for (int k = 0; k < KM; ++k) u[k] = 0.0f;
        if (node < N) {
            int beg = off[node], end = off[node + 1];
            for (int e = beg + l; e < end; e += 8) {
                int s = nbr[e];
                float2 q = aggxd[s];
                float w = q.y;
                float xa = q.x * invA;
                float tx = xa + xa;
                float c0 = 1.0f, c1 = xa;
                u[0] += w;
                u[1] = fmaf(w, c1, u[1]);
                #pragma unroll
                for (int k = 2; k < KM; ++k) {
                    float c2 = fmaf(tx, c1, -c0);
                    u[k] = fmaf(w, c2, u[k]);
                    c0 = c1; c1 = c2;
                }
            }
        }
        #pragma unroll
        for (int k = 0; k < KM; ++k) {
            u[k] += __shfl_down(u[k], 4, 8);
            u[k] += __shfl_down(u[k], 2, 8);
            u[k] += __shfl_down(u[k], 1, 8);
        }
        if (l == 0 && node < N) {
            float2 sd = aggxd[node];
            float d0 = sd.y;
            float d00 = d0 * d0;
            float xa = sd.x * invA;
            float tx = xa + xa;
            float c0 = 1.0f, c1 = xa;
            sM[g][0] = fmaf(d0, u[0], d00);
            sM[g][1] = fmaf(d0, u[1], d00 * xa);
            #pragma unroll
            for (int k = 2; k < KM; ++k) {
                float c2 = fmaf(tx, c1, -c0);
                sM[g][k] = fmaf(d0, u[k], d00 * c2);
                c0 = c1; c1 = c2;
            }
        }
    }
    __syncthreads();
    // ---- phase 2: h2 + pooling (2-node ILP unroll) ----
    double pl = 0.0;
    int gcur = -1;
    int nlim = min(P7_NODES, N - base);
    int i = 0;
    for (; i + 1 < nlim; i += 2) {
        float p0 = bb, p1 = 0.f, p2 = 0.f, p3 = 0.f;
        float q0 = bb, q1 = 0.f, q2 = 0.f, q3 = 0.f;
        const float4* mA = (const float4*)&sM[i][0];
        const float4* mB = (const float4*)&sM[i + 1][0];
        #pragma unroll
        for (int k = 0; k < KM / 4; ++k) {
            float4 a = mA[k];
            float4 c = mB[k];
            p0 = fmaf(a.x, d4[k].x, p0); q0 = fmaf(c.x, d4[k].x, q0);
            p1 = fmaf(a.y, d4[k].y, p1); q1 = fmaf(c.y, d4[k].y, q1);
            p2 = fmaf(a.z, d4[k].z, p2); q2 = fmaf(c.z, d4[k].z, q2);
            p3 = fmaf(a.w, d4[k].w, p3); q3 = fmaf(c.w, d4[k].w, q3);
        }
        float preA = (p0 + p1) + (p2 + p3);
        float preB = (q0 + q1) + (q2 + q3);
        float hA = silu_fast(preA);
        float hB = silu_fast(preB);
        int g = sbatch[i];
        if (g != gcur) {
            if (gcur >= 0 && act) atomicAdd(&pooled[(size_t)gcur * F2 + m], pl);
            pl = 0.0;
            gcur = g;
        }
        if (act) pl += (double)hA;
        g = sbatch[i + 1];
        if (g != gcur) {
            if (gcur >= 0 && act) atomicAdd(&pooled[(size_t)gcur * F2 + m], pl);
            pl = 0.0;
            gcur = g;
        }
        if (act) pl += (double)hB;
    }
    if (i < nlim) {
        float p0 = bb, p1 = 0.f, p2 = 0.f, p3 = 0.f;
        const float4* mA = (const float4*)&sM[i][0];
        #pragma unroll
        for (int k = 0; k < KM / 4; ++k) {
            float4 a = mA[k];
            p0 = fmaf(a.x, d4[k].x, p0);
            p1 = fmaf(a.y, d4[k].y, p1);
            p2 = fmaf(a.z, d4[k].z, p2);
            p3 = fmaf(a.w, d4[k].w, p3);
        }
        float pre = (p0 + p1) + (p2 + p3);
        int g = sbatch[i];
        if (g != gcur) {
            if (gcur >= 0 && act) atomicAdd(&pooled[(size_t)gcur * F2 + m], pl);
            pl = 0.0;
            gcur = g;
        }
        if (act) pl += (double)silu_fast(pre);
    }
    if (gcur >= 0 && act) atomicAdd(&pooled[(size_t)gcur * F2 + m], pl);
}

// ---- fallback path kernels (ws too small for pairs) ----
#define SCHUNK 2048
__global__ __launch_bounds__(256) void k_scan_partial(const int* __restrict__ deg, int N,
                                                      int* __restrict__ partials) {
    __shared__ int red[256];
    int base = blockIdx.x * SCHUNK;
    int s = 0;
    for (int i = threadIdx.x; i < SCHUNK; i += 256) {
        int idx = base + i;
        if (idx < N) s += deg[idx];
    }
    red[threadIdx.x] = s;
    __syncthreads();
    for (int ofs = 128; ofs > 0; ofs >>= 1) {
        if (threadIdx.x < ofs) red[threadIdx.x] += red[threadIdx.x + ofs];
        __syncthreads();
    }
    if (threadIdx.x == 0) partials[blockIdx.x] = red[0];
}
__global__ __launch_bounds__(1024) void k_scan_blocks(int* __restrict__ partials, int nb) {
    __shared__ int sh[1024];
    int t = threadIdx.x;
    int v = (t < nb) ? partials[t] : 0;
    sh[t] = v;
    __syncthreads();
    for (int ofs = 1; ofs < 1024; ofs <<= 1) {
        int u = (t >= ofs) ? sh[t - ofs] : 0;
        __syncthreads();
        sh[t] += u;
        __syncthreads();
    }
    if (t < nb) partials[t] = sh[t] - v;
}
__global__ __launch_bounds__(256) void k_scan_final(const int* __restrict__ deg, int N,
                                                    const int* __restrict__ partials,
                                                    int* __restrict__ off) {
    __shared__ int sh[256];
    int base = blockIdx.x * SCHUNK;
    int i0 = base + threadIdx.x * 8;
    int v[8];
    int s = 0;
    #pragma unroll
    for (int j = 0; j < 8; ++j) {
        int idx = i0 + j;
        v[j] = (idx < N) ? deg[idx] : 0;
        s += v[j];
    }
    int mine = s;
    sh[threadIdx.x] = s;
    __syncthreads();
    for (int ofs = 1; ofs < 256; ofs <<= 1) {
        int u = (threadIdx.x >= ofs) ? sh[threadIdx.x - ofs] : 0;
        __syncthreads();
        sh[threadIdx.x] += u;
        __syncthreads();
    }
    int run = partials[blockIdx.x] + sh[threadIdx.x] - mine;
    #pragma unroll
    for (int j = 0; j < 8; ++j) {
        int idx = i0 + j;
        if (idx < N) { off[idx] = run; run += v[j]; }
    }
    if (N >= i0 && N <= i0 + 8) off[N] = run;
}
__global__ void k_count_deg(const int* __restrict__ dst, int E, int* __restrict__ deg) {
    int i = blockIdx.x * blockDim.x + threadIdx.x;
    if (i < E) atomicAdd(&deg[dst[i]], 1);
}
__global__ void k_dinv_self(const int* __restrict__ deg, const float* __restrict__ x, int N,
                            float* __restrict__ dinv, float* __restrict__ aggx) {
    int i = blockIdx.x * blockDim.x + threadIdx.x;
    if (i < N) {
        float d = 1.0f / sqrtf((float)deg[i] + 1.0f);
        dinv[i] = d;
        aggx[i] = x[i] * d * d;
    }
}
__global__ void k_fill_agg(const int* __restrict__ src, const int* __restrict__ dst, int E,
                           const int* __restrict__ off, int* __restrict__ cursor,
                           int* __restrict__ nbr,
                           const float* __restrict__ x, const float* __restrict__ dinv,
                           float* __restrict__ aggx) {
    int e = blockIdx.x * blockDim.x + threadIdx.x;
    if (e < E) {
        int s = src[e], d = dst[e];
        int p = atomicAdd(&cursor[d], 1);
        nbr[off[d] + p] = s;
        atomicAdd(&aggx[d], x[s] * dinv[s] * dinv[d]);
    }
}
__global__ __launch_bounds__(256) void k_aggh(
    const int* __restrict__ off, const int* __restrict__ nbr,
    const float* __restrict__ aggx, const float* __restrict__ dinv,
    const float* __restrict__ W1, const float* __restrict__ b1,
    int N, float* __restrict__ aggh) {
    int wave = threadIdx.x >> 6;
    int lane = threadIdx.x & 63;
    int n = blockIdx.x * 4 + wave;
    if (n >= N) return;
    int ja = lane, jb = lane + 64;
    float w1a = (ja < F1) ? W1[ja] : 0.0f;
    float b1a = (ja < F1) ? b1[ja] : 0.0f;
    float w1b = (jb < F1) ? W1[jb] : 0.0f;
    float b1b = (jb < F1) ? b1[jb] : 0.0f;
    float d0 = dinv[n];
    float a0 = aggx[n];
    float accA = silu_fast(fmaf(a0, w1a, b1a)) * (d0 * d0);
    float accB = silu_fast(fmaf(a0, w1b, b1b)) * (d0 * d0);
    int beg = off[n], end = off[n + 1];
    for (int t = beg; t < end; t += 64) {
        int cnt = min(64, end - t);
        float sa = 0.0f, sw = 0.0f;
        if (lane < cnt) {
            int s = nbr[t + lane];
            sa = aggx[s];
            sw = dinv[s] * d0;
        }
        for (int i = 0; i < cnt; ++i) {
            float ai = __shfl(sa, i);
            float wi = __shfl(sw, i);
            accA = fmaf(wi, silu_fast(fmaf(ai, w1a, b1a)), accA);
            accB = fmaf(wi, silu_fast(fmaf(ai, w1b, b1b)), accB);
        }
    }
    if (ja < F1) aggh[(size_t)n * F1 + ja] = accA;
    if (jb < F1) aggh[(size_t)n * F1 + jb] = accB;
}
#define HP_NODES 20
#define HP_KT 25
__global__ __launch_bounds__(256) void k_h2_pool3(
    const float* __restrict__ aggh, const float* __restrict__ W2, const float* __restrict__ b2,
    const int* __restrict__ batch, int N, double* __restrict__ pooled) {
    __shared__ float smem[HP_KT * F2 + HP_NODES * (F1 + 1)];
    float* sW = smem;
    float* sA = smem + HP_KT * F2;
    float* sOut = smem;
    __shared__ int sbatch[HP_NODES];
    int tid = threadIdx.x;
    int base = blockIdx.x * HP_NODES;
    for (int idx = tid; idx < HP_NODES * (F1 / 4); idx += 256) {
        int i = idx / (F1 / 4), q = idx % (F1 / 4);
        int n = base + i;
        float4 v = make_float4(0.f, 0.f, 0.f, 0.f);
        if (n < N) v = *(const float4*)(aggh + (size_t)n * F1 + q * 4);
        float* dp = &sA[i * (F1 + 1) + q * 4];
        dp[0] = v.x; dp[1] = v.y; dp[2] = v.z; dp[3] = v.w;
    }
    if (tid < HP_NODES) {
        int n = base + tid;
        sbatch[tid] = (n < N) ? batch[n] : -1;
    }
    const int fgrp = tid % 50;
    const int ngrp = tid / 50;
    const int m0 = fgrp * 4;
    const int i0 = ngrp * 4;
    const bool act = (tid < 250);
    float acc[4][4];
    #pragma unroll
    for (int i = 0; i < 4; ++i)
        #pragma unroll
        for (int j = 0; j < 4; ++j) acc[i][j] = 0.0f;
    for (int kt = 0; kt < F1; kt += HP_KT) {
        __syncthreads();
        for (int idx = tid; idx < (HP_KT * F2) / 4; idx += 256)
            ((float4*)sW)[idx] = ((const float4*)(W2 + (size_t)kt * F2))[idx];
        __syncthreads();
        if (act) {
            #pragma unroll
            for (int kk = 0; kk < HP_KT; ++kk) {
                float4 w = *(const float4*)&sW[kk * F2 + m0];
                int k = kt + kk;
                float a0 = sA[(i0 + 0) * (F1 + 1) + k];
                float a1 = sA[(i0 + 1) * (F1 + 1) + k];
                float a2 = sA[(i0 + 2) * (F1 + 1) + k];
                float a3 = sA[(i0 + 3) * (F1 + 1) + k];
                acc[0][0] = fmaf(a0, w.x, acc[0][0]); acc[0][1] = fmaf(a0, w.y, acc[0][1]);
                acc[0][2] = fmaf(a0, w.z, acc[0][2]); acc[0][3] = fmaf(a0, w.w, acc[0][3]);
                acc[1][0] = fmaf(a1, w.x, acc[1][0]); acc[1][1] = fmaf(a1, w.y, acc[1][1]);
                acc[1][2] = fmaf(a1, w.z, acc[1][2]); acc[1][3] = fmaf(a1, w.w, acc[1][3]);
                acc[2][0] = fmaf(a2, w.x, acc[2][0]); acc[2][1] = fmaf(a2, w.y, acc[2][1]);
                acc[2][2] = fmaf(a2, w.z, acc[2][2]); acc[2][3] = fmaf(a2, w.w, acc[2][3]);
                acc[3][0] = fmaf(a3, w.x, acc[3][0]); acc[3][1] = fmaf(a3, w.y, acc[3][1]);
                acc[3][2] = fmaf(a3, w.z, acc[3][2]); acc[3][3] = fmaf(a3, w.w, acc[3][3]);
            }
        }
    }
    __syncthreads();
    if (act) {
        float4 bb = *(const float4*)(b2 + m0);
        #pragma unroll
        for (int i = 0; i < 4; ++i) {
            float4 r;
            r.x = siluf(acc[i][0] + bb.x);
            r.y = siluf(acc[i][1] + bb.y);
            r.z = siluf(acc[i][2] + bb.z);
            r.w = siluf(acc[i][3] + bb.w);
            *(float4*)&sOut[(i0 + i) * F2 + m0] = r;
        }
    }
    __syncthreads();
    if (tid < F2) {
        double pl = 0.0;
        int gcur = -1;
        for (int i = 0; i < HP_NODES; ++i) {
            int n = base + i;
            if (n >= N) break;
            int g = sbatch[i];
            if (g != gcur) {
                if (gcur >= 0) atomicAdd(&pooled[(size_t)gcur * F2 + tid], pl);
                pl = 0.0;
                gcur = g;
            }
            pl += (double)sOut[i * F2 + tid];
        }
        if (gcur >= 0) atomicAdd(&pooled[(size_t)gcur * F2 + tid], pl);
    }
}

// Head MLP: one block per graph, double precision.
__global__ __launch_bounds__(256) void k_head(
    const double* __restrict__ pooled, const int* __restrict__ counts,
    const float* __restrict__ Wl1, const float* __restrict__ bl1,
    const float* __restrict__ Wl2, const float* __restrict__ bl2,
    float* __restrict__ out) {
    int g = blockIdx.x;
    int tid = threadIdx.x;
    __shared__ double sp[F2];
    __shared__ double red[256];
    double icnt = 1.0 / (double)max(counts[g], 1);
    for (int m = tid; m < F2; m += 256) sp[m] = pooled[(size_t)g * F2 + m] * icnt;
    __syncthreads();
    double part = 0.0;
    if (tid < 100) {
        double acc = (double)bl1[tid];
        #pragma unroll 4
        for (int m = 0; m < F2; ++m) acc += sp[m] * (double)Wl1[m * 100 + tid];
        double t1 = acc / (1.0 + exp(-acc));
        part = t1 * (double)Wl2[tid];
    }
    red[tid] = part;
    __syncthreads();
    for (int s = 128; s > 0; s >>= 1) {
        if (tid < s) red[tid] += red[tid + s];
        __syncthreads();
    }
    if (tid == 0) out[g] = (float)(red[0] + (double)bl2[0]);
}

extern "C" void kernel_launch(void* const* d_in, const int* in_sizes, int n_in,
                              void* d_out, int out_size, void* d_ws, size_t ws_size,
                              hipStream_t stream)
{
    const float* x   = (const float*)d_in[0];
    const int*   src = (const int*)d_in[1];
    const int*   dst = (const int*)d_in[2];
    const int*   batch = (const int*)d_in[3];
    const float* W1  = (const float*)d_in[4];
    const float* b1  = (const float*)d_in[5];
    const float* W2  = (const float*)d_in[6];
    const float* b2  = (const float*)d_in[7];
    const float* Wl1 = (const float*)d_in[8];
    const float* bl1 = (const float*)d_in[9];
    const float* Wl2 = (const float*)d_in[10];
    const float* bl2 = (const float*)d_in[11];
    int N = in_sizes[0];
    int E = in_sizes[1];
    int G = out_size;
    float* out = (float*)d_out;

    char* ws = (char*)d_ws;
    size_t o = 0;
    auto alloc = [&](size_t bytes) -> void* {
        o = (o + 255) & ~(size_t)255;
        void* p = ws + o;
        o += bytes;
        return p;
    };
    int nscan = (N + SCHUNK - 1) / SCHUNK;
    int nbk = (N + BW - 1) / BW;
    int*    deg    = (int*)alloc((size_t)N * 4);
    int*    cursor = (int*)alloc((size_t)N * 4);
    int*    off    = (int*)alloc((size_t)(N + 1) * 4);
    int*    nbr    = (int*)alloc((size_t)E * 4);
    float*  dinv   = (float*)alloc((size_t)N * 4);
    float*  aggx   = (float*)alloc((size_t)N * 4);   // fallback only
    float*  yv     = (float*)alloc((size_t)N * 4);   // y = x*dinv (bucket path)
    float*  aggh   = (float*)alloc((size_t)N * F1 * 4);  // fallback only
    double* pooled = (double*)alloc((size_t)G * F2 * 8);
    int*    counts = (int*)alloc((size_t)G * 4);
    int*    starts = (int*)alloc((size_t)(G + 1) * 4);
    int*    partials = (int*)alloc((size_t)nscan * 4);
    int*    bcnt   = (int*)alloc((size_t)nbk * 4);
    int*    bbase  = (int*)alloc((size_t)(nbk + 1) * 4);
    int*    bcur   = (int*)alloc((size_t)nbk * 4);
    float2* aggxd  = (float2*)alloc((size_t)N * 8);
    float*  Dmat   = (float*)alloc((size_t)KM * F2 * 4);
    double* clbuf  = (double*)alloc((size_t)KM * F1 * 8);
    float*  scal   = (float*)alloc(2 * 4);
    unsigned* amaxb = (unsigned*)alloc(4);
    // gated large buffer: bucketed edge pairs (last)
    o = (o + 255) & ~(size_t)255;
    unsigned long long* pairs = (unsigned long long*)(ws + o);
    bool use_bucket = (o + (size_t)E * 8) <= ws_size;

    int tE = (E + 255) / 256;
    int tN = (N + 255) / 256;

    if (use_bucket) {
        k_prep<<<PREP_BLOCKS, 256, 0, stream>>>(batch, N, G, nbk, starts, counts, pooled, bcnt, amaxb);
        k_bucket_count<<<240, 256, nbk * 4, stream>>>(dst, E, nbk, bcnt);
        k_bucket_scan<<<1, 256, 0, stream>>>(bcnt, nbk, E, bbase, bcur);
        k_bucket_scatter<<<240, 256, 0, stream>>>(src, dst, E, nbk, bcur, pairs);
        k_bucket_degoff<<<nbk, 512, 0, stream>>>(pairs, bbase, x, N, dinv, yv, off);
        k_bucket_fill<<<nbk, 512, 0, stream>>>(pairs, bbase, off, yv, dinv, N, nbr, aggxd, amaxb);
        k_fit_coef<<<F1, 64, 0, stream>>>(W1, b1, amaxb, clbuf, scal);
        k_fit_fold<<<(KM * F2 + 255) / 256, 256, 0, stream>>>(clbuf, W2, Dmat);
        k_h2_pool7<<<(N + P7_NODES - 1) / P7_NODES, 256, 0, stream>>>(
            off, nbr, aggxd, scal, Dmat, b2, batch, N, pooled);
    } else {
        k_prep<<<PREP_BLOCKS, 256, 0, stream>>>(batch, N, G, nbk, starts, counts, pooled, bcnt, amaxb);
        hipMemsetAsync(deg, 0, (size_t)N * 4, stream);
        hipMemsetAsync(cursor, 0, (size_t)N * 4, stream);
        k_count_deg<<<tE, 256, 0, stream>>>(dst, E, deg);
        k_dinv_self<<<tN, 256, 0, stream>>>(deg, x, N, dinv, aggx);
        k_scan_partial<<<nscan, 256, 0, stream>>>(deg, N, partials);
        k_scan_blocks<<<1, 1024, 0, stream>>>(partials, nscan);
        k_scan_final<<<nscan, 256, 0, stream>>>(deg, N, partials, off);
        k_fill_agg<<<tE, 256, 0, stream>>>(src, dst, E, off, cursor, nbr, x, dinv, aggx);
        k_aggh<<<(N + 3) / 4, 256, 0, stream>>>(off, nbr, aggx, dinv, W1, b1, N, aggh);
        k_h2_pool3<<<(N + HP_NODES - 1) / HP_NODES, 256, 0, stream>>>(aggh, W2, b2, batch, N, pooled);
    }
    k_head<<<G, 256, 0, stream>>>(pooled, counts, Wl1, bl1, Wl2, bl2, out);
}